// Round 1
// baseline (2544.158 us; speedup 1.0000x reference)
//
#include <hip/hip_runtime.h>

#define ND 64   // feature dim
#define NR 8    // num edge types

// ---------------------------------------------------------------- zero
__global__ __launch_bounds__(256) void zero_kernel(float4* __restrict__ p, long n4) {
    long i = (long)blockIdx.x * 256 + threadIdx.x;
    long stride = (long)gridDim.x * 256;
    float4 z = make_float4(0.f, 0.f, 0.f, 0.f);
    for (; i < n4; i += stride) p[i] = z;
}

// ---------------------------------------------------------------- scatter
// One 64-lane wave per edge; lane d adds x[src][d] into ag[type*N+dst][d].
__global__ __launch_bounds__(256) void scatter_kernel(
    const float* __restrict__ x, const int* __restrict__ src,
    const int* __restrict__ dst, const int* __restrict__ typ,
    float* __restrict__ ag, int nEdges, int nNodes)
{
    int e = blockIdx.x * 4 + (threadIdx.x >> 6);
    if (e >= nEdges) return;
    int d = threadIdx.x & 63;
    int s  = src[e];
    int dd = dst[e];
    int t  = typ[e];
    float v = x[(long)s * ND + d];
    atomicAdd(ag + ((long)t * nNodes + dd) * ND + d, v);
}

// ---------------------------------------------------------------- fused node update
// per node: msgs = sum_r ag[r,n,:] @ W[r]   (W[r] staged in LDS per r)
//           h    = (1+eps)*x + msgs
//           out  = relu(h@mw1+mb1)@mw2 + mb2 + bias
__global__ __launch_bounds__(256) void node_kernel(
    const float* __restrict__ x, const float* __restrict__ ag,
    const float* __restrict__ W, const float* __restrict__ bias,
    const float* __restrict__ eps,
    const float* __restrict__ mw1, const float* __restrict__ mb1,
    const float* __restrict__ mw2, const float* __restrict__ mb2,
    float* __restrict__ out, int nNodes)
{
    __shared__ float w_lds[ND * ND];
    __shared__ float m1_lds[ND * ND];
    __shared__ float m2_lds[ND * ND];

    int tid = threadIdx.x;
    int node = blockIdx.x * 256 + tid;
    bool active = node < nNodes;

    for (int i = tid; i < ND * ND; i += 256) {
        m1_lds[i] = mw1[i];
        m2_lds[i] = mw2[i];
    }

    float acc[ND];
#pragma unroll
    for (int o = 0; o < ND; ++o) acc[o] = 0.f;

    for (int r = 0; r < NR; ++r) {
        __syncthreads();
        for (int i = tid; i < ND * ND; i += 256) w_lds[i] = W[r * ND * ND + i];
        __syncthreads();
        if (active) {
            const float4* agr = (const float4*)(ag + ((long)r * nNodes + node) * ND);
#pragma unroll 4
            for (int i4 = 0; i4 < ND / 4; ++i4) {
                float4 a4 = agr[i4];
#pragma unroll
                for (int k = 0; k < 4; ++k) {
                    float a = (k == 0) ? a4.x : (k == 1) ? a4.y : (k == 2) ? a4.z : a4.w;
                    const float4* wrow = (const float4*)(w_lds + (i4 * 4 + k) * ND);
#pragma unroll
                    for (int o4 = 0; o4 < ND / 4; ++o4) {
                        float4 w4 = wrow[o4];
                        acc[o4 * 4 + 0] += a * w4.x;
                        acc[o4 * 4 + 1] += a * w4.y;
                        acc[o4 * 4 + 2] += a * w4.z;
                        acc[o4 * 4 + 3] += a * w4.w;
                    }
                }
            }
        }
    }

    if (!active) return;

    float epsv = 1.0f + eps[0];

    // h = (1+eps)*x + msgs  (in place into acc)
    const float4* xr = (const float4*)(x + (long)node * ND);
#pragma unroll
    for (int i4 = 0; i4 < ND / 4; ++i4) {
        float4 x4 = xr[i4];
        acc[i4 * 4 + 0] += epsv * x4.x;
        acc[i4 * 4 + 1] += epsv * x4.y;
        acc[i4 * 4 + 2] += epsv * x4.z;
        acc[i4 * 4 + 3] += epsv * x4.w;
    }

    // t = relu(h @ mw1 + mb1)
    float t[ND];
#pragma unroll
    for (int o = 0; o < ND; ++o) t[o] = mb1[o];
    for (int i = 0; i < ND; ++i) {
        float a = acc[i];
        const float4* mrow = (const float4*)(m1_lds + i * ND);
#pragma unroll
        for (int o4 = 0; o4 < ND / 4; ++o4) {
            float4 w4 = mrow[o4];
            t[o4 * 4 + 0] += a * w4.x;
            t[o4 * 4 + 1] += a * w4.y;
            t[o4 * 4 + 2] += a * w4.z;
            t[o4 * 4 + 3] += a * w4.w;
        }
    }
#pragma unroll
    for (int o = 0; o < ND; ++o) t[o] = fmaxf(t[o], 0.f);

    // out = t @ mw2 + mb2 + bias
    float oacc[ND];
#pragma unroll
    for (int o = 0; o < ND; ++o) oacc[o] = mb2[o] + bias[o];
    for (int i = 0; i < ND; ++i) {
        float a = t[i];
        const float4* mrow = (const float4*)(m2_lds + i * ND);
#pragma unroll
        for (int o4 = 0; o4 < ND / 4; ++o4) {
            float4 w4 = mrow[o4];
            oacc[o4 * 4 + 0] += a * w4.x;
            oacc[o4 * 4 + 1] += a * w4.y;
            oacc[o4 * 4 + 2] += a * w4.z;
            oacc[o4 * 4 + 3] += a * w4.w;
        }
    }

    float4* outr = (float4*)(out + (long)node * ND);
#pragma unroll
    for (int o4 = 0; o4 < ND / 4; ++o4)
        outr[o4] = make_float4(oacc[o4 * 4 + 0], oacc[o4 * 4 + 1],
                               oacc[o4 * 4 + 2], oacc[o4 * 4 + 3]);
}

// ---------------------------------------------------------------- launch
extern "C" void kernel_launch(void* const* d_in, const int* in_sizes, int n_in,
                              void* d_out, int out_size, void* d_ws, size_t ws_size,
                              hipStream_t stream) {
    const float* x    = (const float*)d_in[0];
    const int* esrc   = (const int*)d_in[1];
    const int* edst   = (const int*)d_in[2];
    const int* etyp   = (const int*)d_in[3];

    const float* W1   = (const float*)d_in[4];
    const float* b1   = (const float*)d_in[5];
    const float* e1   = (const float*)d_in[6];
    const float* m1w1 = (const float*)d_in[7];
    const float* m1b1 = (const float*)d_in[8];
    const float* m1w2 = (const float*)d_in[9];
    const float* m1b2 = (const float*)d_in[10];

    const float* W2   = (const float*)d_in[11];
    const float* b2   = (const float*)d_in[12];
    const float* e2   = (const float*)d_in[13];
    const float* m2w1 = (const float*)d_in[14];
    const float* m2b1 = (const float*)d_in[15];
    const float* m2w2 = (const float*)d_in[16];
    const float* m2b2 = (const float*)d_in[17];

    int nNodes = in_sizes[0] / ND;   // 50000
    int nEdges = in_sizes[1];        // 1600000

    float* ag = (float*)d_ws;                          // [R*N*D]
    float* h  = ag + (long)NR * nNodes * ND;           // [N*D]
    float* outp = (float*)d_out;

    long agN4 = (long)NR * nNodes * ND / 4;
    int zgrid = 2048;
    int sgrid = (nEdges + 3) / 4;
    int ngrid = (nNodes + 255) / 256;

    // ---- layer 1
    zero_kernel<<<zgrid, 256, 0, stream>>>((float4*)ag, agN4);
    scatter_kernel<<<sgrid, 256, 0, stream>>>(x, esrc, edst, etyp, ag, nEdges, nNodes);
    node_kernel<<<ngrid, 256, 0, stream>>>(x, ag, W1, b1, e1, m1w1, m1b1, m1w2, m1b2, h, nNodes);

    // ---- layer 2
    zero_kernel<<<zgrid, 256, 0, stream>>>((float4*)ag, agN4);
    scatter_kernel<<<sgrid, 256, 0, stream>>>(h, esrc, edst, etyp, ag, nEdges, nNodes);
    node_kernel<<<ngrid, 256, 0, stream>>>(h, ag, W2, b2, e2, m2w1, m2b1, m2w2, m2b2, outp, nNodes);
}

// Round 2
// 1108.608 us; speedup vs baseline: 2.2949x; 2.2949x over previous
//
#include <hip/hip_runtime.h>

#define ND 64   // feature dim
#define NR 8    // num edge types

// ---------------------------------------------------------------- zero
__global__ __launch_bounds__(256) void zero_kernel(float4* __restrict__ p, long n4) {
    long i = (long)blockIdx.x * 256 + threadIdx.x;
    long stride = (long)gridDim.x * 256;
    float4 z = make_float4(0.f, 0.f, 0.f, 0.f);
    for (; i < n4; i += stride) p[i] = z;
}

// ---------------------------------------------------------------- scatter
// One 64-lane wave per edge; lane d adds x[src][d] into ag[type*N+dst][d].
__global__ __launch_bounds__(256) void scatter_kernel(
    const float* __restrict__ x, const int* __restrict__ src,
    const int* __restrict__ dst, const int* __restrict__ typ,
    float* __restrict__ ag, int nEdges, int nNodes)
{
    int e = blockIdx.x * 4 + (threadIdx.x >> 6);
    if (e >= nEdges) return;
    int d = threadIdx.x & 63;
    int s  = src[e];
    int dd = dst[e];
    int t  = typ[e];
    float v = x[(long)s * ND + d];
    atomicAdd(ag + ((long)t * nNodes + dd) * ND + d, v);
}

// ---------------------------------------------------------------- fused node update
// One thread per node. NO LDS, NO runtime-indexed register arrays.
// Weights are read via wave-uniform addresses -> scalar loads (K$), so the
// vector pipe only does FMAs + the ag/x row streams.
__global__ __launch_bounds__(256, 2) void node_kernel(
    const float* __restrict__ x, const float* __restrict__ ag,
    const float* __restrict__ W, const float* __restrict__ bias,
    const float* __restrict__ eps,
    const float* __restrict__ mw1, const float* __restrict__ mb1,
    const float* __restrict__ mw2, const float* __restrict__ mb2,
    float* __restrict__ out, int nNodes)
{
    int node = blockIdx.x * 256 + threadIdx.x;
    bool active = node < nNodes;
    int nc = active ? node : (nNodes - 1);   // clamp for loads; store predicated

    float epsv = 1.0f + eps[0];

    // h = (1+eps)*x   (then accumulate msgs into it)
    float h[ND];
    {
        const float4* xr = (const float4*)(x + (long)nc * ND);
#pragma unroll
        for (int i4 = 0; i4 < ND / 4; ++i4) {
            float4 x4 = xr[i4];
            h[4 * i4 + 0] = epsv * x4.x;
            h[4 * i4 + 1] = epsv * x4.y;
            h[4 * i4 + 2] = epsv * x4.z;
            h[4 * i4 + 3] = epsv * x4.w;
        }
    }

    // h += sum_r ag[r,node,:] @ W[r]
    for (int r = 0; r < NR; ++r) {
        const float4* agr = (const float4*)(ag + ((long)r * nNodes + nc) * ND);
        const float* wr = W + r * ND * ND;          // wave-uniform base
#pragma unroll 2
        for (int i4 = 0; i4 < ND / 4; ++i4) {
            float4 a4 = agr[i4];
            const float* af = (const float*)&a4;
#pragma unroll
            for (int k = 0; k < 4; ++k) {
                float a = af[k];
                const float* wrow = wr + (i4 * 4 + k) * ND;   // uniform addr -> s_load
#pragma unroll
                for (int o = 0; o < ND; ++o)
                    h[o] = fmaf(a, wrow[o], h[o]);
            }
        }
    }

    // t = relu(h @ mw1 + mb1)   -- fully unrolled, constant indices only
    float t[ND];
#pragma unroll
    for (int o = 0; o < ND; ++o) t[o] = mb1[o];
#pragma unroll
    for (int i = 0; i < ND; ++i) {
        float a = h[i];
        const float* wrow = mw1 + i * ND;            // uniform const addr -> s_load
#pragma unroll
        for (int o = 0; o < ND; ++o)
            t[o] = fmaf(a, wrow[o], t[o]);
    }
#pragma unroll
    for (int o = 0; o < ND; ++o) t[o] = fmaxf(t[o], 0.f);

    // oacc = t @ mw2 + mb2 + bias
    float oacc[ND];
#pragma unroll
    for (int o = 0; o < ND; ++o) oacc[o] = mb2[o] + bias[o];
#pragma unroll
    for (int i = 0; i < ND; ++i) {
        float a = t[i];
        const float* wrow = mw2 + i * ND;            // uniform const addr -> s_load
#pragma unroll
        for (int o = 0; o < ND; ++o)
            oacc[o] = fmaf(a, wrow[o], oacc[o]);
    }

    if (!active) return;
    float4* outr = (float4*)(out + (long)node * ND);
#pragma unroll
    for (int o4 = 0; o4 < ND / 4; ++o4)
        outr[o4] = make_float4(oacc[4 * o4 + 0], oacc[4 * o4 + 1],
                               oacc[4 * o4 + 2], oacc[4 * o4 + 3]);
}

// ---------------------------------------------------------------- launch
extern "C" void kernel_launch(void* const* d_in, const int* in_sizes, int n_in,
                              void* d_out, int out_size, void* d_ws, size_t ws_size,
                              hipStream_t stream) {
    const float* x    = (const float*)d_in[0];
    const int* esrc   = (const int*)d_in[1];
    const int* edst   = (const int*)d_in[2];
    const int* etyp   = (const int*)d_in[3];

    const float* W1   = (const float*)d_in[4];
    const float* b1   = (const float*)d_in[5];
    const float* e1   = (const float*)d_in[6];
    const float* m1w1 = (const float*)d_in[7];
    const float* m1b1 = (const float*)d_in[8];
    const float* m1w2 = (const float*)d_in[9];
    const float* m1b2 = (const float*)d_in[10];

    const float* W2   = (const float*)d_in[11];
    const float* b2   = (const float*)d_in[12];
    const float* e2   = (const float*)d_in[13];
    const float* m2w1 = (const float*)d_in[14];
    const float* m2b1 = (const float*)d_in[15];
    const float* m2w2 = (const float*)d_in[16];
    const float* m2b2 = (const float*)d_in[17];

    int nNodes = in_sizes[0] / ND;   // 50000
    int nEdges = in_sizes[1];        // 1600000

    float* ag = (float*)d_ws;                          // [R*N*D]
    float* h  = ag + (long)NR * nNodes * ND;           // [N*D]
    float* outp = (float*)d_out;

    long agN4 = (long)NR * nNodes * ND / 4;
    int zgrid = 2048;
    int sgrid = (nEdges + 3) / 4;
    int ngrid = (nNodes + 255) / 256;

    // ---- layer 1
    zero_kernel<<<zgrid, 256, 0, stream>>>((float4*)ag, agN4);
    scatter_kernel<<<sgrid, 256, 0, stream>>>(x, esrc, edst, etyp, ag, nEdges, nNodes);
    node_kernel<<<ngrid, 256, 0, stream>>>(x, ag, W1, b1, e1, m1w1, m1b1, m1w2, m1b2, h, nNodes);

    // ---- layer 2
    zero_kernel<<<zgrid, 256, 0, stream>>>((float4*)ag, agN4);
    scatter_kernel<<<sgrid, 256, 0, stream>>>(h, esrc, edst, etyp, ag, nEdges, nNodes);
    node_kernel<<<ngrid, 256, 0, stream>>>(h, ag, W2, b2, e2, m2w1, m2b1, m2w2, m2b2, outp, nNodes);
}

// Round 3
// 815.953 us; speedup vs baseline: 3.1180x; 1.3587x over previous
//
#include <hip/hip_runtime.h>

#define ND 64   // feature dim
#define NR 8    // num edge types
#define SCAN_BLOCK 256
#define SCAN_ELEMS 1024

// ---------------------------------------------------------------- zero ints
__global__ __launch_bounds__(256) void zeroi_kernel(int* __restrict__ p, int n) {
    int i = blockIdx.x * 256 + threadIdx.x;
    int stride = gridDim.x * 256;
    for (; i < n; i += stride) p[i] = 0;
}

// ---------------------------------------------------------------- histogram
__global__ __launch_bounds__(256) void hist_kernel(
    const int* __restrict__ dst, const int* __restrict__ typ,
    int* __restrict__ cnt, int nEdges, int nNodes)
{
    int e = blockIdx.x * 256 + threadIdx.x;
    if (e < nEdges) atomicAdd(cnt + typ[e] * nNodes + dst[e], 1);
}

// ---------------------------------------------------------------- scan (3 kernels)
__global__ __launch_bounds__(SCAN_BLOCK) void scan1_kernel(
    const int* __restrict__ counts, int* __restrict__ offsets,
    int* __restrict__ blockSums, int S)
{
    __shared__ int lds[SCAN_BLOCK];
    int base = blockIdx.x * SCAN_ELEMS;
    int tid = threadIdx.x;
    int v[4]; int lsum = 0;
#pragma unroll
    for (int k = 0; k < 4; ++k) {
        int i = base + tid * 4 + k;
        v[k] = (i < S) ? counts[i] : 0;
        lsum += v[k];
    }
    lds[tid] = lsum;
    __syncthreads();
    int x = lsum;
    for (int off = 1; off < SCAN_BLOCK; off <<= 1) {
        int y = (tid >= off) ? lds[tid - off] : 0;
        __syncthreads();
        x += y;
        lds[tid] = x;
        __syncthreads();
    }
    int run = x - lsum;  // exclusive prefix of this thread's 4 elems
#pragma unroll
    for (int k = 0; k < 4; ++k) {
        int i = base + tid * 4 + k;
        if (i < S) offsets[i] = run;
        run += v[k];
    }
    if (tid == SCAN_BLOCK - 1) blockSums[blockIdx.x] = x;  // block total
}

__global__ __launch_bounds__(512) void scan2_kernel(
    const int* __restrict__ blockSums, int* __restrict__ blockOffs, int nb)
{
    __shared__ int lds[512];
    int tid = threadIdx.x;
    int v = (tid < nb) ? blockSums[tid] : 0;
    lds[tid] = v;
    __syncthreads();
    int x = v;
    for (int off = 1; off < 512; off <<= 1) {
        int y = (tid >= off) ? lds[tid - off] : 0;
        __syncthreads();
        x += y;
        lds[tid] = x;
        __syncthreads();
    }
    if (tid < nb) blockOffs[tid] = x - v;
}

__global__ __launch_bounds__(SCAN_BLOCK) void scan3_kernel(
    int* __restrict__ offsets, int* __restrict__ cursor,
    const int* __restrict__ blockOffs, int S, int nEdges)
{
    int base = blockIdx.x * SCAN_ELEMS;
    int add = blockOffs[blockIdx.x];
#pragma unroll
    for (int k = 0; k < 4; ++k) {
        int i = base + threadIdx.x + k * SCAN_BLOCK;
        if (i < S) {
            int v = offsets[i] + add;
            offsets[i] = v;
            cursor[i] = v;
        }
    }
    if (blockIdx.x == 0 && threadIdx.x == 0) offsets[S] = nEdges;
}

// ---------------------------------------------------------------- permute (counting-sort scatter of src ids)
__global__ __launch_bounds__(256) void permute_kernel(
    const int* __restrict__ src, const int* __restrict__ dst,
    const int* __restrict__ typ, int* __restrict__ cursor,
    int* __restrict__ perm, int nEdges, int nNodes)
{
    int e = blockIdx.x * 256 + threadIdx.x;
    if (e < nEdges) {
        int seg = typ[e] * nNodes + dst[e];
        int pos = atomicAdd(cursor + seg, 1);
        perm[pos] = src[e];
    }
}

// ---------------------------------------------------------------- gather: ag[seg] = sum x[src] over segment
__global__ __launch_bounds__(256) void gather_kernel(
    const float* __restrict__ x, const int* __restrict__ offsets,
    const int* __restrict__ perm, float* __restrict__ ag, int S)
{
    int s = blockIdx.x * 4 + (threadIdx.x >> 6);
    if (s >= S) return;
    int lane = threadIdx.x & 63;
    int beg = offsets[s], end = offsets[s + 1];
    float acc = 0.f;
    int p = beg;
    for (; p + 1 < end; p += 2) {
        int s0 = perm[p], s1 = perm[p + 1];
        float v0 = x[(long)s0 * ND + lane];
        float v1 = x[(long)s1 * ND + lane];
        acc += v0 + v1;
    }
    if (p < end) acc += x[(long)perm[p] * ND + lane];
    ag[(long)s * ND + lane] = acc;
}

// ---------------------------------------------------------------- fused node update (unchanged from R2)
__global__ __launch_bounds__(256, 2) void node_kernel(
    const float* __restrict__ x, const float* __restrict__ ag,
    const float* __restrict__ W, const float* __restrict__ bias,
    const float* __restrict__ eps,
    const float* __restrict__ mw1, const float* __restrict__ mb1,
    const float* __restrict__ mw2, const float* __restrict__ mb2,
    float* __restrict__ out, int nNodes)
{
    int node = blockIdx.x * 256 + threadIdx.x;
    bool active = node < nNodes;
    int nc = active ? node : (nNodes - 1);

    float epsv = 1.0f + eps[0];

    float h[ND];
    {
        const float4* xr = (const float4*)(x + (long)nc * ND);
#pragma unroll
        for (int i4 = 0; i4 < ND / 4; ++i4) {
            float4 x4 = xr[i4];
            h[4 * i4 + 0] = epsv * x4.x;
            h[4 * i4 + 1] = epsv * x4.y;
            h[4 * i4 + 2] = epsv * x4.z;
            h[4 * i4 + 3] = epsv * x4.w;
        }
    }

    for (int r = 0; r < NR; ++r) {
        const float4* agr = (const float4*)(ag + ((long)r * nNodes + nc) * ND);
        const float* wr = W + r * ND * ND;
#pragma unroll 2
        for (int i4 = 0; i4 < ND / 4; ++i4) {
            float4 a4 = agr[i4];
            const float* af = (const float*)&a4;
#pragma unroll
            for (int k = 0; k < 4; ++k) {
                float a = af[k];
                const float* wrow = wr + (i4 * 4 + k) * ND;
#pragma unroll
                for (int o = 0; o < ND; ++o)
                    h[o] = fmaf(a, wrow[o], h[o]);
            }
        }
    }

    float t[ND];
#pragma unroll
    for (int o = 0; o < ND; ++o) t[o] = mb1[o];
#pragma unroll
    for (int i = 0; i < ND; ++i) {
        float a = h[i];
        const float* wrow = mw1 + i * ND;
#pragma unroll
        for (int o = 0; o < ND; ++o)
            t[o] = fmaf(a, wrow[o], t[o]);
    }
#pragma unroll
    for (int o = 0; o < ND; ++o) t[o] = fmaxf(t[o], 0.f);

    float oacc[ND];
#pragma unroll
    for (int o = 0; o < ND; ++o) oacc[o] = mb2[o] + bias[o];
#pragma unroll
    for (int i = 0; i < ND; ++i) {
        float a = t[i];
        const float* wrow = mw2 + i * ND;
#pragma unroll
        for (int o = 0; o < ND; ++o)
            oacc[o] = fmaf(a, wrow[o], oacc[o]);
    }

    if (!active) return;
    float4* outr = (float4*)(out + (long)node * ND);
#pragma unroll
    for (int o4 = 0; o4 < ND / 4; ++o4)
        outr[o4] = make_float4(oacc[4 * o4 + 0], oacc[4 * o4 + 1],
                               oacc[4 * o4 + 2], oacc[4 * o4 + 3]);
}

// ---------------------------------------------------------------- launch
extern "C" void kernel_launch(void* const* d_in, const int* in_sizes, int n_in,
                              void* d_out, int out_size, void* d_ws, size_t ws_size,
                              hipStream_t stream) {
    const float* x    = (const float*)d_in[0];
    const int* esrc   = (const int*)d_in[1];
    const int* edst   = (const int*)d_in[2];
    const int* etyp   = (const int*)d_in[3];

    const float* W1   = (const float*)d_in[4];
    const float* b1   = (const float*)d_in[5];
    const float* e1   = (const float*)d_in[6];
    const float* m1w1 = (const float*)d_in[7];
    const float* m1b1 = (const float*)d_in[8];
    const float* m1w2 = (const float*)d_in[9];
    const float* m1b2 = (const float*)d_in[10];

    const float* W2   = (const float*)d_in[11];
    const float* b2   = (const float*)d_in[12];
    const float* e2   = (const float*)d_in[13];
    const float* m2w1 = (const float*)d_in[14];
    const float* m2b1 = (const float*)d_in[15];
    const float* m2w2 = (const float*)d_in[16];
    const float* m2b2 = (const float*)d_in[17];

    int nNodes = in_sizes[0] / ND;   // 50000
    int nEdges = in_sizes[1];        // 1600000
    int S = NR * nNodes;             // 400000 segments
    int nb = (S + SCAN_ELEMS - 1) / SCAN_ELEMS;  // 391

    // ---- workspace layout (fits in previously-proven 115.2 MB footprint)
    float* ag      = (float*)d_ws;                       // R*N*ND floats = 102.4 MB
    int*   iws     = (int*)(ag + (long)NR * nNodes * ND);
    int*   offsets = iws;                                // S+1
    int*   cnt_cur = offsets + (S + 1);                  // S (counts, then cursor)
    int*   blockSums = cnt_cur + S;                      // nb
    int*   blockOffs = blockSums + 512;                  // nb
    int*   perm    = blockOffs + 512;                    // E
    float* h       = (float*)d_out;                      // layer-1 output aliases d_out (safe)
    float* outp    = (float*)d_out;

    int egrid = (nEdges + 255) / 256;
    int ggrid = (S + 3) / 4;
    int ngrid = (nNodes + 255) / 256;

    // ---- build CSR once (graph shared by both layers)
    zeroi_kernel<<<512, 256, 0, stream>>>(cnt_cur, S);
    hist_kernel<<<egrid, 256, 0, stream>>>(edst, etyp, cnt_cur, nEdges, nNodes);
    scan1_kernel<<<nb, SCAN_BLOCK, 0, stream>>>(cnt_cur, offsets, blockSums, S);
    scan2_kernel<<<1, 512, 0, stream>>>(blockSums, blockOffs, nb);
    scan3_kernel<<<nb, SCAN_BLOCK, 0, stream>>>(offsets, cnt_cur, blockOffs, S, nEdges);
    permute_kernel<<<egrid, 256, 0, stream>>>(esrc, edst, etyp, cnt_cur, perm, nEdges, nNodes);

    // ---- layer 1
    gather_kernel<<<ggrid, 256, 0, stream>>>(x, offsets, perm, ag, S);
    node_kernel<<<ngrid, 256, 0, stream>>>(x, ag, W1, b1, e1, m1w1, m1b1, m1w2, m1b2, h, nNodes);

    // ---- layer 2
    gather_kernel<<<ggrid, 256, 0, stream>>>(h, offsets, perm, ag, S);
    node_kernel<<<ngrid, 256, 0, stream>>>(h, ag, W2, b2, e2, m2w1, m2b1, m2w2, m2b2, outp, nNodes);
}

// Round 4
// 697.431 us; speedup vs baseline: 3.6479x; 1.1699x over previous
//
#include <hip/hip_runtime.h>

#define ND 64   // feature dim
#define NR 8    // num edge types
#define SCAN_BLOCK 256
#define SCAN_ELEMS 1024

// ---------------------------------------------------------------- zero ints
__global__ __launch_bounds__(256) void zeroi_kernel(int* __restrict__ p, int n) {
    int i = blockIdx.x * 256 + threadIdx.x;
    int stride = gridDim.x * 256;
    for (; i < n; i += stride) p[i] = 0;
}

// ---------------------------------------------------------------- histogram
__global__ __launch_bounds__(256) void hist_kernel(
    const int* __restrict__ dst, const int* __restrict__ typ,
    int* __restrict__ cnt, int nEdges, int nNodes)
{
    int e = blockIdx.x * 256 + threadIdx.x;
    if (e < nEdges) atomicAdd(cnt + typ[e] * nNodes + dst[e], 1);
}

// ---------------------------------------------------------------- scan (3 kernels)
__global__ __launch_bounds__(SCAN_BLOCK) void scan1_kernel(
    const int* __restrict__ counts, int* __restrict__ offsets,
    int* __restrict__ blockSums, int S)
{
    __shared__ int lds[SCAN_BLOCK];
    int base = blockIdx.x * SCAN_ELEMS;
    int tid = threadIdx.x;
    int v[4]; int lsum = 0;
#pragma unroll
    for (int k = 0; k < 4; ++k) {
        int i = base + tid * 4 + k;
        v[k] = (i < S) ? counts[i] : 0;
        lsum += v[k];
    }
    lds[tid] = lsum;
    __syncthreads();
    int x = lsum;
    for (int off = 1; off < SCAN_BLOCK; off <<= 1) {
        int y = (tid >= off) ? lds[tid - off] : 0;
        __syncthreads();
        x += y;
        lds[tid] = x;
        __syncthreads();
    }
    int run = x - lsum;
#pragma unroll
    for (int k = 0; k < 4; ++k) {
        int i = base + tid * 4 + k;
        if (i < S) offsets[i] = run;
        run += v[k];
    }
    if (tid == SCAN_BLOCK - 1) blockSums[blockIdx.x] = x;
}

__global__ __launch_bounds__(512) void scan2_kernel(
    const int* __restrict__ blockSums, int* __restrict__ blockOffs, int nb)
{
    __shared__ int lds[512];
    int tid = threadIdx.x;
    int v = (tid < nb) ? blockSums[tid] : 0;
    lds[tid] = v;
    __syncthreads();
    int x = v;
    for (int off = 1; off < 512; off <<= 1) {
        int y = (tid >= off) ? lds[tid - off] : 0;
        __syncthreads();
        x += y;
        lds[tid] = x;
        __syncthreads();
    }
    if (tid < nb) blockOffs[tid] = x - v;
}

__global__ __launch_bounds__(SCAN_BLOCK) void scan3_kernel(
    int* __restrict__ offsets, int* __restrict__ cursor,
    const int* __restrict__ blockOffs, int S, int nEdges)
{
    int base = blockIdx.x * SCAN_ELEMS;
    int add = blockOffs[blockIdx.x];
#pragma unroll
    for (int k = 0; k < 4; ++k) {
        int i = base + threadIdx.x + k * SCAN_BLOCK;
        if (i < S) {
            int v = offsets[i] + add;
            offsets[i] = v;
            cursor[i] = v;
        }
    }
    if (blockIdx.x == 0 && threadIdx.x == 0) offsets[S] = nEdges;
}

// ---------------------------------------------------------------- permute
__global__ __launch_bounds__(256) void permute_kernel(
    const int* __restrict__ src, const int* __restrict__ dst,
    const int* __restrict__ typ, int* __restrict__ cursor,
    int* __restrict__ perm, int nEdges, int nNodes)
{
    int e = blockIdx.x * 256 + threadIdx.x;
    if (e < nEdges) {
        int seg = typ[e] * nNodes + dst[e];
        int pos = atomicAdd(cursor + seg, 1);
        perm[pos] = src[e];
    }
}

// ---------------------------------------------------------------- gather
__global__ __launch_bounds__(256) void gather_kernel(
    const float* __restrict__ x, const int* __restrict__ offsets,
    const int* __restrict__ perm, float* __restrict__ ag, int S)
{
    int s = blockIdx.x * 4 + (threadIdx.x >> 6);
    if (s >= S) return;
    int lane = threadIdx.x & 63;
    int beg = offsets[s], end = offsets[s + 1];
    float acc = 0.f;
    int p = beg;
    for (; p + 1 < end; p += 2) {
        int s0 = perm[p], s1 = perm[p + 1];
        float v0 = x[(long)s0 * ND + lane];
        float v1 = x[(long)s1 * ND + lane];
        acc += v0 + v1;
    }
    if (p < end) acc += x[(long)perm[p] * ND + lane];
    ag[(long)s * ND + lane] = acc;
}

// ---------------------------------------------------------------- fused node update
// 4 lanes (a "quad") per node; lane owns a 16-feature output slice.
// a-operand broadcast via __shfl from quad-mates (all reg-resident,
// constant-indexed); weights broadcast from LDS (16-lane same-address).
// Block 256 threads = 64 nodes; grid 782 -> ~3 blocks/CU, 12 waves/CU.
__global__ __launch_bounds__(256, 2) void node_kernel(
    const float* __restrict__ x, const float* __restrict__ ag,
    const float* __restrict__ W, const float* __restrict__ bias,
    const float* __restrict__ eps,
    const float* __restrict__ mw1, const float* __restrict__ mb1,
    const float* __restrict__ mw2, const float* __restrict__ mb2,
    float* __restrict__ out, int nNodes)
{
    __shared__ float w_lds[ND * ND];

    int tid  = threadIdx.x;
    int lane = tid & 63;
    int quad = tid & 3;                 // output-slice id (0..3)
    int nl   = tid >> 2;                // node within block (0..63)
    int node = blockIdx.x * 64 + nl;
    bool active = node < nNodes;
    int nc = active ? node : (nNodes - 1);

    float epsv = 1.0f + eps[0];
    int obase = quad * 16;              // this lane's output/feature slice base

    // ---- h slice = (1+eps) * x[node][obase..obase+16)
    float h[16];
    {
        const float4* xr = (const float4*)(x + (long)nc * ND + obase);
#pragma unroll
        for (int k = 0; k < 4; ++k) {
            float4 v = xr[k];
            h[4 * k + 0] = epsv * v.x; h[4 * k + 1] = epsv * v.y;
            h[4 * k + 2] = epsv * v.z; h[4 * k + 3] = epsv * v.w;
        }
    }

    // ---- msgs: h += sum_r ag[r,node,:] @ W[r]
    for (int r = 0; r < NR; ++r) {
        __syncthreads();
        {   // stage W[r] into LDS: 256 threads x 16 floats
            const float4* wg = (const float4*)(W + (long)r * ND * ND) + tid * 4;
            float4* wl = (float4*)w_lds + tid * 4;
#pragma unroll
            for (int k = 0; k < 4; ++k) wl[k] = wg[k];
        }
        // this lane's a-slice: ag[r,node][obase..obase+16)
        float a[16];
        {
            const float4* agr = (const float4*)(ag + ((long)r * nNodes + nc) * ND + obase);
#pragma unroll
            for (int k = 0; k < 4; ++k) {
                float4 v = agr[k];
                a[4 * k + 0] = v.x; a[4 * k + 1] = v.y;
                a[4 * k + 2] = v.z; a[4 * k + 3] = v.w;
            }
        }
        __syncthreads();
#pragma unroll
        for (int i = 0; i < ND; ++i) {
            float ai = __shfl(a[i & 15], (lane & 60) | (i >> 4));
            const float4* wr4 = (const float4*)(w_lds + i * ND + obase);
            float4 w0 = wr4[0], w1 = wr4[1], w2 = wr4[2], w3 = wr4[3];
            h[0]  = fmaf(ai, w0.x, h[0]);  h[1]  = fmaf(ai, w0.y, h[1]);
            h[2]  = fmaf(ai, w0.z, h[2]);  h[3]  = fmaf(ai, w0.w, h[3]);
            h[4]  = fmaf(ai, w1.x, h[4]);  h[5]  = fmaf(ai, w1.y, h[5]);
            h[6]  = fmaf(ai, w1.z, h[6]);  h[7]  = fmaf(ai, w1.w, h[7]);
            h[8]  = fmaf(ai, w2.x, h[8]);  h[9]  = fmaf(ai, w2.y, h[9]);
            h[10] = fmaf(ai, w2.z, h[10]); h[11] = fmaf(ai, w2.w, h[11]);
            h[12] = fmaf(ai, w3.x, h[12]); h[13] = fmaf(ai, w3.y, h[13]);
            h[14] = fmaf(ai, w3.z, h[14]); h[15] = fmaf(ai, w3.w, h[15]);
        }
    }

    // ---- t = relu(h @ mw1 + mb1)
    __syncthreads();
    {
        const float4* wg = (const float4*)mw1 + tid * 4;
        float4* wl = (float4*)w_lds + tid * 4;
#pragma unroll
        for (int k = 0; k < 4; ++k) wl[k] = wg[k];
    }
    float t[16];
    {
        const float4* br = (const float4*)(mb1 + obase);
#pragma unroll
        for (int k = 0; k < 4; ++k) {
            float4 v = br[k];
            t[4 * k + 0] = v.x; t[4 * k + 1] = v.y;
            t[4 * k + 2] = v.z; t[4 * k + 3] = v.w;
        }
    }
    __syncthreads();
#pragma unroll
    for (int i = 0; i < ND; ++i) {
        float hi = __shfl(h[i & 15], (lane & 60) | (i >> 4));
        const float4* wr4 = (const float4*)(w_lds + i * ND + obase);
        float4 w0 = wr4[0], w1 = wr4[1], w2 = wr4[2], w3 = wr4[3];
        t[0]  = fmaf(hi, w0.x, t[0]);  t[1]  = fmaf(hi, w0.y, t[1]);
        t[2]  = fmaf(hi, w0.z, t[2]);  t[3]  = fmaf(hi, w0.w, t[3]);
        t[4]  = fmaf(hi, w1.x, t[4]);  t[5]  = fmaf(hi, w1.y, t[5]);
        t[6]  = fmaf(hi, w1.z, t[6]);  t[7]  = fmaf(hi, w1.w, t[7]);
        t[8]  = fmaf(hi, w2.x, t[8]);  t[9]  = fmaf(hi, w2.y, t[9]);
        t[10] = fmaf(hi, w2.z, t[10]); t[11] = fmaf(hi, w2.w, t[11]);
        t[12] = fmaf(hi, w3.x, t[12]); t[13] = fmaf(hi, w3.y, t[13]);
        t[14] = fmaf(hi, w3.z, t[14]); t[15] = fmaf(hi, w3.w, t[15]);
    }
#pragma unroll
    for (int j = 0; j < 16; ++j) t[j] = fmaxf(t[j], 0.f);

    // ---- o = t @ mw2 + mb2 + bias
    __syncthreads();
    {
        const float4* wg = (const float4*)mw2 + tid * 4;
        float4* wl = (float4*)w_lds + tid * 4;
#pragma unroll
        for (int k = 0; k < 4; ++k) wl[k] = wg[k];
    }
    float o[16];
    {
        const float4* b2r = (const float4*)(mb2 + obase);
        const float4* bbr = (const float4*)(bias + obase);
#pragma unroll
        for (int k = 0; k < 4; ++k) {
            float4 v = b2r[k], u = bbr[k];
            o[4 * k + 0] = v.x + u.x; o[4 * k + 1] = v.y + u.y;
            o[4 * k + 2] = v.z + u.z; o[4 * k + 3] = v.w + u.w;
        }
    }
    __syncthreads();
#pragma unroll
    for (int i = 0; i < ND; ++i) {
        float ti = __shfl(t[i & 15], (lane & 60) | (i >> 4));
        const float4* wr4 = (const float4*)(w_lds + i * ND + obase);
        float4 w0 = wr4[0], w1 = wr4[1], w2 = wr4[2], w3 = wr4[3];
        o[0]  = fmaf(ti, w0.x, o[0]);  o[1]  = fmaf(ti, w0.y, o[1]);
        o[2]  = fmaf(ti, w0.z, o[2]);  o[3]  = fmaf(ti, w0.w, o[3]);
        o[4]  = fmaf(ti, w1.x, o[4]);  o[5]  = fmaf(ti, w1.y, o[5]);
        o[6]  = fmaf(ti, w1.z, o[6]);  o[7]  = fmaf(ti, w1.w, o[7]);
        o[8]  = fmaf(ti, w2.x, o[8]);  o[9]  = fmaf(ti, w2.y, o[9]);
        o[10] = fmaf(ti, w2.z, o[10]); o[11] = fmaf(ti, w2.w, o[11]);
        o[12] = fmaf(ti, w3.x, o[12]); o[13] = fmaf(ti, w3.y, o[13]);
        o[14] = fmaf(ti, w3.z, o[14]); o[15] = fmaf(ti, w3.w, o[15]);
    }

    if (!active) return;
    float4* outr = (float4*)(out + (long)node * ND + obase);
#pragma unroll
    for (int k = 0; k < 4; ++k)
        outr[k] = make_float4(o[4 * k + 0], o[4 * k + 1], o[4 * k + 2], o[4 * k + 3]);
}

// ---------------------------------------------------------------- launch
extern "C" void kernel_launch(void* const* d_in, const int* in_sizes, int n_in,
                              void* d_out, int out_size, void* d_ws, size_t ws_size,
                              hipStream_t stream) {
    const float* x    = (const float*)d_in[0];
    const int* esrc   = (const int*)d_in[1];
    const int* edst   = (const int*)d_in[2];
    const int* etyp   = (const int*)d_in[3];

    const float* W1   = (const float*)d_in[4];
    const float* b1   = (const float*)d_in[5];
    const float* e1   = (const float*)d_in[6];
    const float* m1w1 = (const float*)d_in[7];
    const float* m1b1 = (const float*)d_in[8];
    const float* m1w2 = (const float*)d_in[9];
    const float* m1b2 = (const float*)d_in[10];

    const float* W2   = (const float*)d_in[11];
    const float* b2   = (const float*)d_in[12];
    const float* e2   = (const float*)d_in[13];
    const float* m2w1 = (const float*)d_in[14];
    const float* m2b1 = (const float*)d_in[15];
    const float* m2w2 = (const float*)d_in[16];
    const float* m2b2 = (const float*)d_in[17];

    int nNodes = in_sizes[0] / ND;   // 50000
    int nEdges = in_sizes[1];        // 1600000
    int S = NR * nNodes;             // 400000 segments
    int nb = (S + SCAN_ELEMS - 1) / SCAN_ELEMS;

    float* ag      = (float*)d_ws;                       // R*N*ND floats
    int*   iws     = (int*)(ag + (long)NR * nNodes * ND);
    int*   offsets = iws;                                // S+1
    int*   cnt_cur = offsets + (S + 1);                  // S
    int*   blockSums = cnt_cur + S;
    int*   blockOffs = blockSums + 512;
    int*   perm    = blockOffs + 512;                    // E
    float* h       = (float*)d_out;                      // layer-1 h aliases d_out
    float* outp    = (float*)d_out;

    int egrid = (nEdges + 255) / 256;
    int ggrid = (S + 3) / 4;
    int ngrid = (nNodes + 63) / 64;

    // ---- build CSR once
    zeroi_kernel<<<512, 256, 0, stream>>>(cnt_cur, S);
    hist_kernel<<<egrid, 256, 0, stream>>>(edst, etyp, cnt_cur, nEdges, nNodes);
    scan1_kernel<<<nb, SCAN_BLOCK, 0, stream>>>(cnt_cur, offsets, blockSums, S);
    scan2_kernel<<<1, 512, 0, stream>>>(blockSums, blockOffs, nb);
    scan3_kernel<<<nb, SCAN_BLOCK, 0, stream>>>(offsets, cnt_cur, blockOffs, S, nEdges);
    permute_kernel<<<egrid, 256, 0, stream>>>(esrc, edst, etyp, cnt_cur, perm, nEdges, nNodes);

    // ---- layer 1
    gather_kernel<<<ggrid, 256, 0, stream>>>(x, offsets, perm, ag, S);
    node_kernel<<<ngrid, 256, 0, stream>>>(x, ag, W1, b1, e1, m1w1, m1b1, m1w2, m1b2, h, nNodes);

    // ---- layer 2
    gather_kernel<<<ggrid, 256, 0, stream>>>(h, offsets, perm, ag, S);
    node_kernel<<<ngrid, 256, 0, stream>>>(h, ag, W2, b2, e2, m2w1, m2b1, m2w2, m2b2, outp, nNodes);
}

// Round 5
// 558.436 us; speedup vs baseline: 4.5559x; 1.2489x over previous
//
#include <hip/hip_runtime.h>

#define ND 64   // feature dim
#define NR 8    // num edge types
#define SCAN_BLOCK 256
#define SCAN_ELEMS 1024

typedef __bf16 bf16x8 __attribute__((ext_vector_type(8)));
typedef float f32x4 __attribute__((ext_vector_type(4)));
typedef unsigned short us8 __attribute__((ext_vector_type(8)));

__device__ inline unsigned short bf16_rne(float f) {
    unsigned u = __float_as_uint(f);
    unsigned r = (u + 0x7FFFu + ((u >> 16) & 1u)) >> 16;
    return (unsigned short)r;
}
__device__ inline float bf16_to_f(unsigned short s) {
    return __uint_as_float(((unsigned)s) << 16);
}

// ---------------------------------------------------------------- zero ints
__global__ __launch_bounds__(256) void zeroi_kernel(int* __restrict__ p, int n) {
    int i = blockIdx.x * 256 + threadIdx.x;
    int stride = gridDim.x * 256;
    for (; i < n; i += stride) p[i] = 0;
}

// ---------------------------------------------------------------- histogram
__global__ __launch_bounds__(256) void hist_kernel(
    const int* __restrict__ dst, const int* __restrict__ typ,
    int* __restrict__ cnt, int nEdges, int nNodes)
{
    int e = blockIdx.x * 256 + threadIdx.x;
    if (e < nEdges) atomicAdd(cnt + typ[e] * nNodes + dst[e], 1);
}

// ---------------------------------------------------------------- scan (3 kernels)
__global__ __launch_bounds__(SCAN_BLOCK) void scan1_kernel(
    const int* __restrict__ counts, int* __restrict__ offsets,
    int* __restrict__ blockSums, int S)
{
    __shared__ int lds[SCAN_BLOCK];
    int base = blockIdx.x * SCAN_ELEMS;
    int tid = threadIdx.x;
    int v[4]; int lsum = 0;
#pragma unroll
    for (int k = 0; k < 4; ++k) {
        int i = base + tid * 4 + k;
        v[k] = (i < S) ? counts[i] : 0;
        lsum += v[k];
    }
    lds[tid] = lsum;
    __syncthreads();
    int x = lsum;
    for (int off = 1; off < SCAN_BLOCK; off <<= 1) {
        int y = (tid >= off) ? lds[tid - off] : 0;
        __syncthreads();
        x += y;
        lds[tid] = x;
        __syncthreads();
    }
    int run = x - lsum;
#pragma unroll
    for (int k = 0; k < 4; ++k) {
        int i = base + tid * 4 + k;
        if (i < S) offsets[i] = run;
        run += v[k];
    }
    if (tid == SCAN_BLOCK - 1) blockSums[blockIdx.x] = x;
}

__global__ __launch_bounds__(512) void scan2_kernel(
    const int* __restrict__ blockSums, int* __restrict__ blockOffs, int nb)
{
    __shared__ int lds[512];
    int tid = threadIdx.x;
    int v = (tid < nb) ? blockSums[tid] : 0;
    lds[tid] = v;
    __syncthreads();
    int x = v;
    for (int off = 1; off < 512; off <<= 1) {
        int y = (tid >= off) ? lds[tid - off] : 0;
        __syncthreads();
        x += y;
        lds[tid] = x;
        __syncthreads();
    }
    if (tid < nb) blockOffs[tid] = x - v;
}

__global__ __launch_bounds__(SCAN_BLOCK) void scan3_kernel(
    int* __restrict__ offsets, int* __restrict__ cursor,
    const int* __restrict__ blockOffs, int S, int nEdges)
{
    int base = blockIdx.x * SCAN_ELEMS;
    int add = blockOffs[blockIdx.x];
#pragma unroll
    for (int k = 0; k < 4; ++k) {
        int i = base + threadIdx.x + k * SCAN_BLOCK;
        if (i < S) {
            int v = offsets[i] + add;
            offsets[i] = v;
            cursor[i] = v;
        }
    }
    if (blockIdx.x == 0 && threadIdx.x == 0) offsets[S] = nEdges;
}

// ---------------------------------------------------------------- permute
__global__ __launch_bounds__(256) void permute_kernel(
    const int* __restrict__ src, const int* __restrict__ dst,
    const int* __restrict__ typ, int* __restrict__ cursor,
    int* __restrict__ perm, int nEdges, int nNodes)
{
    int e = blockIdx.x * 256 + threadIdx.x;
    if (e < nEdges) {
        int seg = typ[e] * nNodes + dst[e];
        int pos = atomicAdd(cursor + seg, 1);
        perm[pos] = src[e];
    }
}

// ---------------------------------------------------------------- weight convert+transpose
// wt[o][k] (bf16, [64][512]) = W[k][o]  where k = r*64+i  (W flat is [512][64])
__global__ __launch_bounds__(256) void convw_kernel(
    const float* __restrict__ W, unsigned short* __restrict__ wt)
{
    int idx = blockIdx.x * 256 + threadIdx.x;
    if (idx >= 64 * 512) return;
    int o = idx >> 9, k = idx & 511;
    wt[idx] = bf16_rne(W[(long)k * 64 + o]);
}

// ---------------------------------------------------------------- x -> bf16
__global__ __launch_bounds__(256) void convx_kernel(
    const float4* __restrict__ x, unsigned short* __restrict__ xb, int n8)
{
    int i = blockIdx.x * 256 + threadIdx.x;
    if (i >= n8) return;
    float4 v0 = x[i * 2], v1 = x[i * 2 + 1];
    us8 o;
    o[0] = bf16_rne(v0.x); o[1] = bf16_rne(v0.y);
    o[2] = bf16_rne(v0.z); o[3] = bf16_rne(v0.w);
    o[4] = bf16_rne(v1.x); o[5] = bf16_rne(v1.y);
    o[6] = bf16_rne(v1.z); o[7] = bf16_rne(v1.w);
    *(us8*)(xb + (long)i * 8) = o;
}

// ---------------------------------------------------------------- gather (bf16 in/out, fp32 accum)
// ag_bf[node][r*64 + d] = sum over segment (r,node) of xb[src][d]
__global__ __launch_bounds__(256) void gather_kernel(
    const unsigned short* __restrict__ xb, const int* __restrict__ offsets,
    const int* __restrict__ perm, unsigned short* __restrict__ agbf,
    int S, int nNodes)
{
    int s = blockIdx.x * 4 + (threadIdx.x >> 6);
    if (s >= S) return;
    int lane = threadIdx.x & 63;
    int r = s / nNodes;
    int node = s - r * nNodes;
    int beg = offsets[s], end = offsets[s + 1];
    float acc = 0.f;
    int p = beg;
    for (; p + 1 < end; p += 2) {
        int s0 = perm[p], s1 = perm[p + 1];
        float v0 = bf16_to_f(xb[(long)s0 * ND + lane]);
        float v1 = bf16_to_f(xb[(long)s1 * ND + lane]);
        acc += v0 + v1;
    }
    if (p < end) acc += bf16_to_f(xb[(long)perm[p] * ND + lane]);
    agbf[((long)node * NR + r) * ND + lane] = bf16_rne(acc);
}

// ---------------------------------------------------------------- MFMA einsum
// msgs[M=nodes, 64] = A[M, 512] @ Wt^T   (A = agbf, Wt = [64][512] bf16)
// 32 nodes per wave (2 row-frags x 4 col-tiles), K-loop 16 x 32.
__global__ __launch_bounds__(256) void einsum_kernel(
    const unsigned short* __restrict__ agbf, const unsigned short* __restrict__ wt,
    float* __restrict__ msgs, int nNodes)
{
    int wid = blockIdx.x * 4 + (threadIdx.x >> 6);
    int lane = threadIdx.x & 63;
    int nbase = wid * 32;
    if (nbase >= nNodes) return;
    int r16 = lane & 15;   // A row within subtile / C col
    int kg  = lane >> 4;   // k-group 0..3

    f32x4 acc[2][4];
#pragma unroll
    for (int m = 0; m < 2; ++m)
#pragma unroll
        for (int j = 0; j < 4; ++j) acc[m][j] = (f32x4){0.f, 0.f, 0.f, 0.f};

    int n0 = nbase + r16;      if (n0 >= nNodes) n0 = nNodes - 1;
    int n1 = nbase + 16 + r16; if (n1 >= nNodes) n1 = nNodes - 1;
    const unsigned short* a0p = agbf + (long)n0 * 512 + kg * 8;
    const unsigned short* a1p = agbf + (long)n1 * 512 + kg * 8;
    const unsigned short* bp  = wt + (long)r16 * 512 + kg * 8;

#pragma unroll 4
    for (int kk = 0; kk < 16; ++kk) {
        bf16x8 a0 = *(const bf16x8*)(a0p + kk * 32);
        bf16x8 a1 = *(const bf16x8*)(a1p + kk * 32);
#pragma unroll
        for (int j = 0; j < 4; ++j) {
            bf16x8 b = *(const bf16x8*)(bp + (long)j * 16 * 512 + kk * 32);
            acc[0][j] = __builtin_amdgcn_mfma_f32_16x16x32_bf16(a0, b, acc[0][j], 0, 0, 0);
            acc[1][j] = __builtin_amdgcn_mfma_f32_16x16x32_bf16(a1, b, acc[1][j], 0, 0, 0);
        }
    }

    // C layout (verified m89): col = lane&15, row = (lane>>4)*4 + reg
#pragma unroll
    for (int m = 0; m < 2; ++m) {
#pragma unroll
        for (int reg = 0; reg < 4; ++reg) {
            int row = nbase + m * 16 + kg * 4 + reg;
            if (row < nNodes) {
#pragma unroll
                for (int j = 0; j < 4; ++j)
                    msgs[(long)row * ND + j * 16 + r16] = acc[m][j][reg];
            }
        }
    }
}

// ---------------------------------------------------------------- MLP (quad structure)
// h = (1+eps)*xin + msgs ; out = relu(h@mw1+mb1)@mw2 + mb2 + bias
__global__ __launch_bounds__(256, 2) void mlp_kernel(
    const float* __restrict__ xin, const float* __restrict__ msgs,
    const float* __restrict__ bias, const float* __restrict__ eps,
    const float* __restrict__ mw1, const float* __restrict__ mb1,
    const float* __restrict__ mw2, const float* __restrict__ mb2,
    float* __restrict__ out, unsigned short* __restrict__ out_bf, int nNodes)
{
    __shared__ float w_lds[ND * ND];

    int tid  = threadIdx.x;
    int lane = tid & 63;
    int quad = tid & 3;
    int nl   = tid >> 2;
    int node = blockIdx.x * 64 + nl;
    bool active = node < nNodes;
    int nc = active ? node : (nNodes - 1);

    float epsv = 1.0f + eps[0];
    int obase = quad * 16;

    // ---- h slice = (1+eps)*xin + msgs
    float h[16];
    {
        const float4* xr = (const float4*)(xin + (long)nc * ND + obase);
        const float4* mr = (const float4*)(msgs + (long)nc * ND + obase);
#pragma unroll
        for (int k = 0; k < 4; ++k) {
            float4 v = xr[k], m = mr[k];
            h[4 * k + 0] = fmaf(epsv, v.x, m.x); h[4 * k + 1] = fmaf(epsv, v.y, m.y);
            h[4 * k + 2] = fmaf(epsv, v.z, m.z); h[4 * k + 3] = fmaf(epsv, v.w, m.w);
        }
    }

    // ---- t = relu(h @ mw1 + mb1)
    {
        const float4* wg = (const float4*)mw1 + tid * 4;
        float4* wl = (float4*)w_lds + tid * 4;
#pragma unroll
        for (int k = 0; k < 4; ++k) wl[k] = wg[k];
    }
    float t[16];
    {
        const float4* br = (const float4*)(mb1 + obase);
#pragma unroll
        for (int k = 0; k < 4; ++k) {
            float4 v = br[k];
            t[4 * k + 0] = v.x; t[4 * k + 1] = v.y;
            t[4 * k + 2] = v.z; t[4 * k + 3] = v.w;
        }
    }
    __syncthreads();
#pragma unroll
    for (int i = 0; i < ND; ++i) {
        float hi = __shfl(h[i & 15], (lane & 60) | (i >> 4));
        const float4* wr4 = (const float4*)(w_lds + i * ND + obase);
        float4 w0 = wr4[0], w1 = wr4[1], w2 = wr4[2], w3 = wr4[3];
        t[0]  = fmaf(hi, w0.x, t[0]);  t[1]  = fmaf(hi, w0.y, t[1]);
        t[2]  = fmaf(hi, w0.z, t[2]);  t[3]  = fmaf(hi, w0.w, t[3]);
        t[4]  = fmaf(hi, w1.x, t[4]);  t[5]  = fmaf(hi, w1.y, t[5]);
        t[6]  = fmaf(hi, w1.z, t[6]);  t[7]  = fmaf(hi, w1.w, t[7]);
        t[8]  = fmaf(hi, w2.x, t[8]);  t[9]  = fmaf(hi, w2.y, t[9]);
        t[10] = fmaf(hi, w2.z, t[10]); t[11] = fmaf(hi, w2.w, t[11]);
        t[12] = fmaf(hi, w3.x, t[12]); t[13] = fmaf(hi, w3.y, t[13]);
        t[14] = fmaf(hi, w3.z, t[14]); t[15] = fmaf(hi, w3.w, t[15]);
    }
#pragma unroll
    for (int j = 0; j < 16; ++j) t[j] = fmaxf(t[j], 0.f);

    // ---- o = t @ mw2 + mb2 + bias
    __syncthreads();
    {
        const float4* wg = (const float4*)mw2 + tid * 4;
        float4* wl = (float4*)w_lds + tid * 4;
#pragma unroll
        for (int k = 0; k < 4; ++k) wl[k] = wg[k];
    }
    float o[16];
    {
        const float4* b2r = (const float4*)(mb2 + obase);
        const float4* bbr = (const float4*)(bias + obase);
#pragma unroll
        for (int k = 0; k < 4; ++k) {
            float4 v = b2r[k], u = bbr[k];
            o[4 * k + 0] = v.x + u.x; o[4 * k + 1] = v.y + u.y;
            o[4 * k + 2] = v.z + u.z; o[4 * k + 3] = v.w + u.w;
        }
    }
    __syncthreads();
#pragma unroll
    for (int i = 0; i < ND; ++i) {
        float ti = __shfl(t[i & 15], (lane & 60) | (i >> 4));
        const float4* wr4 = (const float4*)(w_lds + i * ND + obase);
        float4 w0 = wr4[0], w1 = wr4[1], w2 = wr4[2], w3 = wr4[3];
        o[0]  = fmaf(ti, w0.x, o[0]);  o[1]  = fmaf(ti, w0.y, o[1]);
        o[2]  = fmaf(ti, w0.z, o[2]);  o[3]  = fmaf(ti, w0.w, o[3]);
        o[4]  = fmaf(ti, w1.x, o[4]);  o[5]  = fmaf(ti, w1.y, o[5]);
        o[6]  = fmaf(ti, w1.z, o[6]);  o[7]  = fmaf(ti, w1.w, o[7]);
        o[8]  = fmaf(ti, w2.x, o[8]);  o[9]  = fmaf(ti, w2.y, o[9]);
        o[10] = fmaf(ti, w2.z, o[10]); o[11] = fmaf(ti, w2.w, o[11]);
        o[12] = fmaf(ti, w3.x, o[12]); o[13] = fmaf(ti, w3.y, o[13]);
        o[14] = fmaf(ti, w3.z, o[14]); o[15] = fmaf(ti, w3.w, o[15]);
    }

    if (!active) return;
    float4* outr = (float4*)(out + (long)node * ND + obase);
#pragma unroll
    for (int k = 0; k < 4; ++k)
        outr[k] = make_float4(o[4 * k + 0], o[4 * k + 1], o[4 * k + 2], o[4 * k + 3]);
    if (out_bf != nullptr) {
        us8 b0, b1;
#pragma unroll
        for (int k = 0; k < 8; ++k) { b0[k] = bf16_rne(o[k]); b1[k] = bf16_rne(o[8 + k]); }
        us8* obr = (us8*)(out_bf + (long)node * ND + obase);
        obr[0] = b0; obr[1] = b1;
    }
}

// ---------------------------------------------------------------- launch
extern "C" void kernel_launch(void* const* d_in, const int* in_sizes, int n_in,
                              void* d_out, int out_size, void* d_ws, size_t ws_size,
                              hipStream_t stream) {
    const float* x    = (const float*)d_in[0];
    const int* esrc   = (const int*)d_in[1];
    const int* edst   = (const int*)d_in[2];
    const int* etyp   = (const int*)d_in[3];

    const float* W1   = (const float*)d_in[4];
    const float* b1   = (const float*)d_in[5];
    const float* e1   = (const float*)d_in[6];
    const float* m1w1 = (const float*)d_in[7];
    const float* m1b1 = (const float*)d_in[8];
    const float* m1w2 = (const float*)d_in[9];
    const float* m1b2 = (const float*)d_in[10];

    const float* W2   = (const float*)d_in[11];
    const float* b2   = (const float*)d_in[12];
    const float* e2   = (const float*)d_in[13];
    const float* m2w1 = (const float*)d_in[14];
    const float* m2b1 = (const float*)d_in[15];
    const float* m2w2 = (const float*)d_in[16];
    const float* m2b2 = (const float*)d_in[17];

    int nNodes = in_sizes[0] / ND;   // 50000
    int nEdges = in_sizes[1];        // 1600000
    int S = NR * nNodes;             // 400000
    int nb = (S + SCAN_ELEMS - 1) / SCAN_ELEMS;

    // ---- workspace layout
    unsigned short* agbf = (unsigned short*)d_ws;                 // N*512 bf16 = 51.2MB
    float* msgs   = (float*)(agbf + (long)nNodes * 512);          // N*64 f32 = 12.8MB
    unsigned short* xhbf = (unsigned short*)(msgs + (long)nNodes * ND); // N*64 bf16 = 6.4MB
    unsigned short* wt1 = xhbf + (long)nNodes * ND;               // 64*512 bf16
    unsigned short* wt2 = wt1 + 64 * 512;
    int* offsets = (int*)(wt2 + 64 * 512);                        // S+1
    int* cnt_cur = offsets + (S + 1);                             // S
    int* blockSums = cnt_cur + S;
    int* blockOffs = blockSums + 512;
    int* perm = blockOffs + 512;                                  // E
    float* h    = (float*)d_out;   // layer-1 fp32 h aliases d_out
    float* outp = (float*)d_out;

    int egrid = (nEdges + 255) / 256;
    int ggrid = (S + 3) / 4;
    int mgrid = (nNodes + 63) / 64;
    int esgrid = ((nNodes + 31) / 32 + 3) / 4;
    int n8 = nNodes * ND / 8;

    // ---- build CSR once
    zeroi_kernel<<<512, 256, 0, stream>>>(cnt_cur, S);
    hist_kernel<<<egrid, 256, 0, stream>>>(edst, etyp, cnt_cur, nEdges, nNodes);
    scan1_kernel<<<nb, SCAN_BLOCK, 0, stream>>>(cnt_cur, offsets, blockSums, S);
    scan2_kernel<<<1, 512, 0, stream>>>(blockSums, blockOffs, nb);
    scan3_kernel<<<nb, SCAN_BLOCK, 0, stream>>>(offsets, cnt_cur, blockOffs, S, nEdges);
    permute_kernel<<<egrid, 256, 0, stream>>>(esrc, edst, etyp, cnt_cur, perm, nEdges, nNodes);

    // ---- weight + x converts
    convw_kernel<<<128, 256, 0, stream>>>(W1, wt1);
    convw_kernel<<<128, 256, 0, stream>>>(W2, wt2);
    convx_kernel<<<(n8 + 255) / 256, 256, 0, stream>>>((const float4*)x, xhbf, n8);

    // ---- layer 1
    gather_kernel<<<ggrid, 256, 0, stream>>>(xhbf, offsets, perm, agbf, S, nNodes);
    einsum_kernel<<<esgrid, 256, 0, stream>>>(agbf, wt1, msgs, nNodes);
    mlp_kernel<<<mgrid, 256, 0, stream>>>(x, msgs, b1, e1, m1w1, m1b1, m1w2, m1b2,
                                          h, xhbf, nNodes);

    // ---- layer 2
    gather_kernel<<<ggrid, 256, 0, stream>>>(xhbf, offsets, perm, agbf, S, nNodes);
    einsum_kernel<<<esgrid, 256, 0, stream>>>(agbf, wt2, msgs, nNodes);
    mlp_kernel<<<mgrid, 256, 0, stream>>>(h, msgs, b2, e2, m2w1, m2b1, m2w2, m2b2,
                                          outp, nullptr, nNodes);
}

// Round 6
// 445.409 us; speedup vs baseline: 5.7120x; 1.2538x over previous
//
#include <hip/hip_runtime.h>

#define ND 64   // feature dim
#define NR 8    // num edge types
#define SCAN_BLOCK 256
#define SCAN_ELEMS 1024

typedef __bf16 bf16x8 __attribute__((ext_vector_type(8)));
typedef float f32x4 __attribute__((ext_vector_type(4)));
typedef unsigned short us8 __attribute__((ext_vector_type(8)));

__device__ inline unsigned short bf16_rne(float f) {
    unsigned u = __float_as_uint(f);
    unsigned r = (u + 0x7FFFu + ((u >> 16) & 1u)) >> 16;
    return (unsigned short)r;
}
__device__ inline float bf16_to_f(unsigned short s) {
    return __uint_as_float(((unsigned)s) << 16);
}

// ---------------------------------------------------------------- zero ints
__global__ __launch_bounds__(256) void zeroi_kernel(int* __restrict__ p, int n) {
    int i = blockIdx.x * 256 + threadIdx.x;
    int stride = gridDim.x * 256;
    for (; i < n; i += stride) p[i] = 0;
}

// ---------------------------------------------------------------- histogram
__global__ __launch_bounds__(256) void hist_kernel(
    const int* __restrict__ dst, const int* __restrict__ typ,
    int* __restrict__ cnt, int nEdges, int nNodes)
{
    int e = blockIdx.x * 256 + threadIdx.x;
    if (e < nEdges) atomicAdd(cnt + typ[e] * nNodes + dst[e], 1);
}

// ---------------------------------------------------------------- scan (3 kernels)
__global__ __launch_bounds__(SCAN_BLOCK) void scan1_kernel(
    const int* __restrict__ counts, int* __restrict__ offsets,
    int* __restrict__ blockSums, int S)
{
    __shared__ int lds[SCAN_BLOCK];
    int base = blockIdx.x * SCAN_ELEMS;
    int tid = threadIdx.x;
    int v[4]; int lsum = 0;
#pragma unroll
    for (int k = 0; k < 4; ++k) {
        int i = base + tid * 4 + k;
        v[k] = (i < S) ? counts[i] : 0;
        lsum += v[k];
    }
    lds[tid] = lsum;
    __syncthreads();
    int x = lsum;
    for (int off = 1; off < SCAN_BLOCK; off <<= 1) {
        int y = (tid >= off) ? lds[tid - off] : 0;
        __syncthreads();
        x += y;
        lds[tid] = x;
        __syncthreads();
    }
    int run = x - lsum;
#pragma unroll
    for (int k = 0; k < 4; ++k) {
        int i = base + tid * 4 + k;
        if (i < S) offsets[i] = run;
        run += v[k];
    }
    if (tid == SCAN_BLOCK - 1) blockSums[blockIdx.x] = x;
}

__global__ __launch_bounds__(512) void scan2_kernel(
    const int* __restrict__ blockSums, int* __restrict__ blockOffs, int nb)
{
    __shared__ int lds[512];
    int tid = threadIdx.x;
    int v = (tid < nb) ? blockSums[tid] : 0;
    lds[tid] = v;
    __syncthreads();
    int x = v;
    for (int off = 1; off < 512; off <<= 1) {
        int y = (tid >= off) ? lds[tid - off] : 0;
        __syncthreads();
        x += y;
        lds[tid] = x;
        __syncthreads();
    }
    if (tid < nb) blockOffs[tid] = x - v;
}

__global__ __launch_bounds__(SCAN_BLOCK) void scan3_kernel(
    int* __restrict__ offsets, int* __restrict__ cursor,
    const int* __restrict__ blockOffs, int S, int nEdges)
{
    int base = blockIdx.x * SCAN_ELEMS;
    int add = blockOffs[blockIdx.x];
#pragma unroll
    for (int k = 0; k < 4; ++k) {
        int i = base + threadIdx.x + k * SCAN_BLOCK;
        if (i < S) {
            int v = offsets[i] + add;
            offsets[i] = v;
            cursor[i] = v;
        }
    }
    if (blockIdx.x == 0 && threadIdx.x == 0) offsets[S] = nEdges;
}

// ---------------------------------------------------------------- permute
__global__ __launch_bounds__(256) void permute_kernel(
    const int* __restrict__ src, const int* __restrict__ dst,
    const int* __restrict__ typ, int* __restrict__ cursor,
    int* __restrict__ perm, int nEdges, int nNodes)
{
    int e = blockIdx.x * 256 + threadIdx.x;
    if (e < nEdges) {
        int seg = typ[e] * nNodes + dst[e];
        int pos = atomicAdd(cursor + seg, 1);
        perm[pos] = src[e];
    }
}

// ---------------------------------------------------------------- weight convert+transpose
// wt[o][k] (bf16, [64][512]) = W[k][o]  where k = r*64+i  (W flat is [512][64])
__global__ __launch_bounds__(256) void convw_kernel(
    const float* __restrict__ W, unsigned short* __restrict__ wt)
{
    int idx = blockIdx.x * 256 + threadIdx.x;
    if (idx >= 64 * 512) return;
    int o = idx >> 9, k = idx & 511;
    wt[idx] = bf16_rne(W[(long)k * 64 + o]);
}

// ---------------------------------------------------------------- x -> bf16
__global__ __launch_bounds__(256) void convx_kernel(
    const float4* __restrict__ x, unsigned short* __restrict__ xb, int n8)
{
    int i = blockIdx.x * 256 + threadIdx.x;
    if (i >= n8) return;
    float4 v0 = x[i * 2], v1 = x[i * 2 + 1];
    us8 o;
    o[0] = bf16_rne(v0.x); o[1] = bf16_rne(v0.y);
    o[2] = bf16_rne(v0.z); o[3] = bf16_rne(v0.w);
    o[4] = bf16_rne(v1.x); o[5] = bf16_rne(v1.y);
    o[6] = bf16_rne(v1.z); o[7] = bf16_rne(v1.w);
    *(us8*)(xb + (long)i * 8) = o;
}

// ---------------------------------------------------------------- gather (restructured)
// 16 lanes per segment; lane owns features [4*fl, 4*fl+4) read as ushort4
// (8 B/lane -> 512 B per wave-instr). 4 segments per wave, grid-stride
// persistent (2048 blocks = full residency). fp32 accum in-register,
// bf16 row-slice written once per segment. Empty segments write zeros.
__global__ __launch_bounds__(256) void gather_kernel(
    const unsigned short* __restrict__ xb, const int* __restrict__ offsets,
    const int* __restrict__ perm, unsigned short* __restrict__ agbf,
    int S, int nNodes)
{
    int tid = threadIdx.x;
    int gidx = (blockIdx.x * 256 + tid) >> 4;     // global group id
    int nGroups = (gridDim.x * 256) >> 4;
    int fl = tid & 15;                            // feature slice base / 4

    for (int s = gidx; s < S; s += nGroups) {
        int beg = offsets[s], end = offsets[s + 1];
        float a0 = 0.f, a1 = 0.f, a2 = 0.f, a3 = 0.f;
        for (int p = beg; p < end; ++p) {
            int srcn = perm[p];
            ushort4 v = *(const ushort4*)(xb + (long)srcn * ND + fl * 4);
            a0 += bf16_to_f(v.x); a1 += bf16_to_f(v.y);
            a2 += bf16_to_f(v.z); a3 += bf16_to_f(v.w);
        }
        int r = s / nNodes;
        int node = s - r * nNodes;
        ushort4 o;
        o.x = bf16_rne(a0); o.y = bf16_rne(a1);
        o.z = bf16_rne(a2); o.w = bf16_rne(a3);
        *(ushort4*)(agbf + (long)node * 512 + r * ND + fl * 4) = o;
    }
}

// ---------------------------------------------------------------- MFMA einsum
// msgs[M=nodes, 64] = A[M, 512] @ Wt^T   (A = agbf, Wt = [64][512] bf16)
// 32 nodes per wave (2 row-frags x 4 col-tiles), K-loop 16 x 32.
__global__ __launch_bounds__(256) void einsum_kernel(
    const unsigned short* __restrict__ agbf, const unsigned short* __restrict__ wt,
    float* __restrict__ msgs, int nNodes)
{
    int wid = blockIdx.x * 4 + (threadIdx.x >> 6);
    int lane = threadIdx.x & 63;
    int nbase = wid * 32;
    if (nbase >= nNodes) return;
    int r16 = lane & 15;   // A row within subtile / C col
    int kg  = lane >> 4;   // k-group 0..3

    f32x4 acc[2][4];
#pragma unroll
    for (int m = 0; m < 2; ++m)
#pragma unroll
        for (int j = 0; j < 4; ++j) acc[m][j] = (f32x4){0.f, 0.f, 0.f, 0.f};

    int n0 = nbase + r16;      if (n0 >= nNodes) n0 = nNodes - 1;
    int n1 = nbase + 16 + r16; if (n1 >= nNodes) n1 = nNodes - 1;
    const unsigned short* a0p = agbf + (long)n0 * 512 + kg * 8;
    const unsigned short* a1p = agbf + (long)n1 * 512 + kg * 8;
    const unsigned short* bp  = wt + (long)r16 * 512 + kg * 8;

#pragma unroll 4
    for (int kk = 0; kk < 16; ++kk) {
        bf16x8 a0 = *(const bf16x8*)(a0p + kk * 32);
        bf16x8 a1 = *(const bf16x8*)(a1p + kk * 32);
#pragma unroll
        for (int j = 0; j < 4; ++j) {
            bf16x8 b = *(const bf16x8*)(bp + (long)j * 16 * 512 + kk * 32);
            acc[0][j] = __builtin_amdgcn_mfma_f32_16x16x32_bf16(a0, b, acc[0][j], 0, 0, 0);
            acc[1][j] = __builtin_amdgcn_mfma_f32_16x16x32_bf16(a1, b, acc[1][j], 0, 0, 0);
        }
    }

    // C layout (verified m89): col = lane&15, row = (lane>>4)*4 + reg
#pragma unroll
    for (int m = 0; m < 2; ++m) {
#pragma unroll
        for (int reg = 0; reg < 4; ++reg) {
            int row = nbase + m * 16 + kg * 4 + reg;
            if (row < nNodes) {
#pragma unroll
                for (int j = 0; j < 4; ++j)
                    msgs[(long)row * ND + j * 16 + r16] = acc[m][j][reg];
            }
        }
    }
}

// ---------------------------------------------------------------- MLP (quad structure)
// h = (1+eps)*xin + msgs ; out = relu(h@mw1+mb1)@mw2 + mb2 + bias
__global__ __launch_bounds__(256, 2) void mlp_kernel(
    const float* __restrict__ xin, const float* __restrict__ msgs,
    const float* __restrict__ bias, const float* __restrict__ eps,
    const float* __restrict__ mw1, const float* __restrict__ mb1,
    const float* __restrict__ mw2, const float* __restrict__ mb2,
    float* __restrict__ out, unsigned short* __restrict__ out_bf, int nNodes)
{
    __shared__ float w_lds[ND * ND];

    int tid  = threadIdx.x;
    int lane = tid & 63;
    int quad = tid & 3;
    int nl   = tid >> 2;
    int node = blockIdx.x * 64 + nl;
    bool active = node < nNodes;
    int nc = active ? node : (nNodes - 1);

    float epsv = 1.0f + eps[0];
    int obase = quad * 16;

    // ---- h slice = (1+eps)*xin + msgs
    float h[16];
    {
        const float4* xr = (const float4*)(xin + (long)nc * ND + obase);
        const float4* mr = (const float4*)(msgs + (long)nc * ND + obase);
#pragma unroll
        for (int k = 0; k < 4; ++k) {
            float4 v = xr[k], m = mr[k];
            h[4 * k + 0] = fmaf(epsv, v.x, m.x); h[4 * k + 1] = fmaf(epsv, v.y, m.y);
            h[4 * k + 2] = fmaf(epsv, v.z, m.z); h[4 * k + 3] = fmaf(epsv, v.w, m.w);
        }
    }

    // ---- t = relu(h @ mw1 + mb1)
    {
        const float4* wg = (const float4*)mw1 + tid * 4;
        float4* wl = (float4*)w_lds + tid * 4;
#pragma unroll
        for (int k = 0; k < 4; ++k) wl[k] = wg[k];
    }
    float t[16];
    {
        const float4* br = (const float4*)(mb1 + obase);
#pragma unroll
        for (int k = 0; k < 4; ++k) {
            float4 v = br[k];
            t[4 * k + 0] = v.x; t[4 * k + 1] = v.y;
            t[4 * k + 2] = v.z; t[4 * k + 3] = v.w;
        }
    }
    __syncthreads();
#pragma unroll
    for (int i = 0; i < ND; ++i) {
        float hi = __shfl(h[i & 15], (lane & 60) | (i >> 4));
        const float4* wr4 = (const float4*)(w_lds + i * ND + obase);
        float4 w0 = wr4[0], w1 = wr4[1], w2 = wr4[2], w3 = wr4[3];
        t[0]  = fmaf(hi, w0.x, t[0]);  t[1]  = fmaf(hi, w0.y, t[1]);
        t[2]  = fmaf(hi, w0.z, t[2]);  t[3]  = fmaf(hi, w0.w, t[3]);
        t[4]  = fmaf(hi, w1.x, t[4]);  t[5]  = fmaf(hi, w1.y, t[5]);
        t[6]  = fmaf(hi, w1.z, t[6]);  t[7]  = fmaf(hi, w1.w, t[7]);
        t[8]  = fmaf(hi, w2.x, t[8]);  t[9]  = fmaf(hi, w2.y, t[9]);
        t[10] = fmaf(hi, w2.z, t[10]); t[11] = fmaf(hi, w2.w, t[11]);
        t[12] = fmaf(hi, w3.x, t[12]); t[13] = fmaf(hi, w3.y, t[13]);
        t[14] = fmaf(hi, w3.z, t[14]); t[15] = fmaf(hi, w3.w, t[15]);
    }
#pragma unroll
    for (int j = 0; j < 16; ++j) t[j] = fmaxf(t[j], 0.f);

    // ---- o = t @ mw2 + mb2 + bias
    __syncthreads();
    {
        const float4* wg = (const float4*)mw2 + tid * 4;
        float4* wl = (float4*)w_lds + tid * 4;
#pragma unroll
        for (int k = 0; k < 4; ++k) wl[k] = wg[k];
    }
    float o[16];
    {
        const float4* b2r = (const float4*)(mb2 + obase);
        const float4* bbr = (const float4*)(bias + obase);
#pragma unroll
        for (int k = 0; k < 4; ++k) {
            float4 v = b2r[k], u = bbr[k];
            o[4 * k + 0] = v.x + u.x; o[4 * k + 1] = v.y + u.y;
            o[4 * k + 2] = v.z + u.z; o[4 * k + 3] = v.w + u.w;
        }
    }
    __syncthreads();
#pragma unroll
    for (int i = 0; i < ND; ++i) {
        float ti = __shfl(t[i & 15], (lane & 60) | (i >> 4));
        const float4* wr4 = (const float4*)(w_lds + i * ND + obase);
        float4 w0 = wr4[0], w1 = wr4[1], w2 = wr4[2], w3 = wr4[3];
        o[0]  = fmaf(ti, w0.x, o[0]);  o[1]  = fmaf(ti, w0.y, o[1]);
        o[2]  = fmaf(ti, w0.z, o[2]);  o[3]  = fmaf(ti, w0.w, o[3]);
        o[4]  = fmaf(ti, w1.x, o[4]);  o[5]  = fmaf(ti, w1.y, o[5]);
        o[6]  = fmaf(ti, w1.z, o[6]);  o[7]  = fmaf(ti, w1.w, o[7]);
        o[8]  = fmaf(ti, w2.x, o[8]);  o[9]  = fmaf(ti, w2.y, o[9]);
        o[10] = fmaf(ti, w2.z, o[10]); o[11] = fmaf(ti, w2.w, o[11]);
        o[12] = fmaf(ti, w3.x, o[12]); o[13] = fmaf(ti, w3.y, o[13]);
        o[14] = fmaf(ti, w3.z, o[14]); o[15] = fmaf(ti, w3.w, o[15]);
    }

    if (!active) return;
    float4* outr = (float4*)(out + (long)node * ND + obase);
#pragma unroll
    for (int k = 0; k < 4; ++k)
        outr[k] = make_float4(o[4 * k + 0], o[4 * k + 1], o[4 * k + 2], o[4 * k + 3]);
    if (out_bf != nullptr) {
        us8 b0, b1;
#pragma unroll
        for (int k = 0; k < 8; ++k) { b0[k] = bf16_rne(o[k]); b1[k] = bf16_rne(o[8 + k]); }
        us8* obr = (us8*)(out_bf + (long)node * ND + obase);
        obr[0] = b0; obr[1] = b1;
    }
}

// ---------------------------------------------------------------- launch
extern "C" void kernel_launch(void* const* d_in, const int* in_sizes, int n_in,
                              void* d_out, int out_size, void* d_ws, size_t ws_size,
                              hipStream_t stream) {
    const float* x    = (const float*)d_in[0];
    const int* esrc   = (const int*)d_in[1];
    const int* edst   = (const int*)d_in[2];
    const int* etyp   = (const int*)d_in[3];

    const float* W1   = (const float*)d_in[4];
    const float* b1   = (const float*)d_in[5];
    const float* e1   = (const float*)d_in[6];
    const float* m1w1 = (const float*)d_in[7];
    const float* m1b1 = (const float*)d_in[8];
    const float* m1w2 = (const float*)d_in[9];
    const float* m1b2 = (const float*)d_in[10];

    const float* W2   = (const float*)d_in[11];
    const float* b2   = (const float*)d_in[12];
    const float* e2   = (const float*)d_in[13];
    const float* m2w1 = (const float*)d_in[14];
    const float* m2b1 = (const float*)d_in[15];
    const float* m2w2 = (const float*)d_in[16];
    const float* m2b2 = (const float*)d_in[17];

    int nNodes = in_sizes[0] / ND;   // 50000
    int nEdges = in_sizes[1];        // 1600000
    int S = NR * nNodes;             // 400000
    int nb = (S + SCAN_ELEMS - 1) / SCAN_ELEMS;

    // ---- workspace layout
    unsigned short* agbf = (unsigned short*)d_ws;                 // N*512 bf16 = 51.2MB
    float* msgs   = (float*)(agbf + (long)nNodes * 512);          // N*64 f32 = 12.8MB
    unsigned short* xhbf = (unsigned short*)(msgs + (long)nNodes * ND); // N*64 bf16 = 6.4MB
    unsigned short* wt1 = xhbf + (long)nNodes * ND;               // 64*512 bf16
    unsigned short* wt2 = wt1 + 64 * 512;
    int* offsets = (int*)(wt2 + 64 * 512);                        // S+1
    int* cnt_cur = offsets + (S + 1);                             // S
    int* blockSums = cnt_cur + S;
    int* blockOffs = blockSums + 512;
    int* perm = blockOffs + 512;                                  // E
    float* h    = (float*)d_out;   // layer-1 fp32 h aliases d_out
    float* outp = (float*)d_out;

    int egrid = (nEdges + 255) / 256;
    int ggrid = 2048;                       // persistent: 8192 waves = full residency
    int mgrid = (nNodes + 63) / 64;
    int esgrid = ((nNodes + 31) / 32 + 3) / 4;
    int n8 = nNodes * ND / 8;

    // ---- build CSR once
    zeroi_kernel<<<512, 256, 0, stream>>>(cnt_cur, S);
    hist_kernel<<<egrid, 256, 0, stream>>>(edst, etyp, cnt_cur, nEdges, nNodes);
    scan1_kernel<<<nb, SCAN_BLOCK, 0, stream>>>(cnt_cur, offsets, blockSums, S);
    scan2_kernel<<<1, 512, 0, stream>>>(blockSums, blockOffs, nb);
    scan3_kernel<<<nb, SCAN_BLOCK, 0, stream>>>(offsets, cnt_cur, blockOffs, S, nEdges);
    permute_kernel<<<egrid, 256, 0, stream>>>(esrc, edst, etyp, cnt_cur, perm, nEdges, nNodes);

    // ---- weight + x converts
    convw_kernel<<<128, 256, 0, stream>>>(W1, wt1);
    convw_kernel<<<128, 256, 0, stream>>>(W2, wt2);
    convx_kernel<<<(n8 + 255) / 256, 256, 0, stream>>>((const float4*)x, xhbf, n8);

    // ---- layer 1
    gather_kernel<<<ggrid, 256, 0, stream>>>(xhbf, offsets, perm, agbf, S, nNodes);
    einsum_kernel<<<esgrid, 256, 0, stream>>>(agbf, wt1, msgs, nNodes);
    mlp_kernel<<<mgrid, 256, 0, stream>>>(x, msgs, b1, e1, m1w1, m1b1, m1w2, m1b2,
                                          h, xhbf, nNodes);

    // ---- layer 2
    gather_kernel<<<ggrid, 256, 0, stream>>>(xhbf, offsets, perm, agbf, S, nNodes);
    einsum_kernel<<<esgrid, 256, 0, stream>>>(agbf, wt2, msgs, nNodes);
    mlp_kernel<<<mgrid, 256, 0, stream>>>(h, msgs, b2, e2, m2w1, m2b1, m2w2, m2b2,
                                          outp, nullptr, nNodes);
}

// Round 7
// 401.682 us; speedup vs baseline: 6.3338x; 1.1089x over previous
//
#include <hip/hip_runtime.h>

#define ND 64   // feature dim
#define NR 8    // num edge types
#define SCAN_BLOCK 256
#define SCAN_ELEMS 1024

typedef __bf16 bf16x8 __attribute__((ext_vector_type(8)));
typedef float f32x4 __attribute__((ext_vector_type(4)));
typedef unsigned short us8 __attribute__((ext_vector_type(8)));

__device__ inline unsigned short bf16_rne(float f) {
    unsigned u = __float_as_uint(f);
    unsigned r = (u + 0x7FFFu + ((u >> 16) & 1u)) >> 16;
    return (unsigned short)r;
}
__device__ inline float bf16_to_f(unsigned short s) {
    return __uint_as_float(((unsigned)s) << 16);
}

// ---------------------------------------------------------------- zero ints
__global__ __launch_bounds__(256) void zeroi_kernel(int* __restrict__ p, int n) {
    int i = blockIdx.x * 256 + threadIdx.x;
    int stride = gridDim.x * 256;
    for (; i < n; i += stride) p[i] = 0;
}

// ---------------------------------------------------------------- histogram
__global__ __launch_bounds__(256) void hist_kernel(
    const int* __restrict__ dst, const int* __restrict__ typ,
    int* __restrict__ cnt, int nEdges, int nNodes)
{
    int e = blockIdx.x * 256 + threadIdx.x;
    if (e < nEdges) atomicAdd(cnt + typ[e] * nNodes + dst[e], 1);
}

// ---------------------------------------------------------------- scan (3 kernels)
__global__ __launch_bounds__(SCAN_BLOCK) void scan1_kernel(
    const int* __restrict__ counts, int* __restrict__ offsets,
    int* __restrict__ blockSums, int S)
{
    __shared__ int lds[SCAN_BLOCK];
    int base = blockIdx.x * SCAN_ELEMS;
    int tid = threadIdx.x;
    int v[4]; int lsum = 0;
#pragma unroll
    for (int k = 0; k < 4; ++k) {
        int i = base + tid * 4 + k;
        v[k] = (i < S) ? counts[i] : 0;
        lsum += v[k];
    }
    lds[tid] = lsum;
    __syncthreads();
    int x = lsum;
    for (int off = 1; off < SCAN_BLOCK; off <<= 1) {
        int y = (tid >= off) ? lds[tid - off] : 0;
        __syncthreads();
        x += y;
        lds[tid] = x;
        __syncthreads();
    }
    int run = x - lsum;
#pragma unroll
    for (int k = 0; k < 4; ++k) {
        int i = base + tid * 4 + k;
        if (i < S) offsets[i] = run;
        run += v[k];
    }
    if (tid == SCAN_BLOCK - 1) blockSums[blockIdx.x] = x;
}

__global__ __launch_bounds__(512) void scan2_kernel(
    const int* __restrict__ blockSums, int* __restrict__ blockOffs, int nb)
{
    __shared__ int lds[512];
    int tid = threadIdx.x;
    int v = (tid < nb) ? blockSums[tid] : 0;
    lds[tid] = v;
    __syncthreads();
    int x = v;
    for (int off = 1; off < 512; off <<= 1) {
        int y = (tid >= off) ? lds[tid - off] : 0;
        __syncthreads();
        x += y;
        lds[tid] = x;
        __syncthreads();
    }
    if (tid < nb) blockOffs[tid] = x - v;
}

__global__ __launch_bounds__(SCAN_BLOCK) void scan3_kernel(
    int* __restrict__ offsets, int* __restrict__ cursor,
    const int* __restrict__ blockOffs, int S, int nEdges)
{
    int base = blockIdx.x * SCAN_ELEMS;
    int add = blockOffs[blockIdx.x];
#pragma unroll
    for (int k = 0; k < 4; ++k) {
        int i = base + threadIdx.x + k * SCAN_BLOCK;
        if (i < S) {
            int v = offsets[i] + add;
            offsets[i] = v;
            cursor[i] = v;
        }
    }
    if (blockIdx.x == 0 && threadIdx.x == 0) offsets[S] = nEdges;
}

// ---------------------------------------------------------------- permute (XCD-sliced)
// Grid = 256 chunks x 8 dst-slices. Block b: chunk=b>>3, slice=b&7.
// blockIdx->XCD is round-robin mod 8, so all blocks of one slice run on one
// XCD; every perm/cursor line then has a single writing XCD -> one writeback
// (kills the 8x partial-line write amplification seen in R6: 109MB for 6.4MB).
// Coverage is exact regardless of the physical XCD mapping.
__global__ __launch_bounds__(256) void permute_kernel(
    const int* __restrict__ src, const int* __restrict__ dst,
    const int* __restrict__ typ, int* __restrict__ cursor,
    int* __restrict__ perm, int nEdges, int nNodes,
    int chunkSize, int sliceSize)
{
    int chunk = blockIdx.x >> 3;
    int slice = blockIdx.x & 7;
    int lo = slice * sliceSize;
    int hi = lo + sliceSize;
    int beg = chunk * chunkSize;
    int end = min(beg + chunkSize, nEdges);
    for (int e = beg + threadIdx.x; e < end; e += 256) {
        int d = dst[e];
        if (d >= lo && d < hi) {
            int seg = typ[e] * nNodes + d;
            int pos = atomicAdd(cursor + seg, 1);
            perm[pos] = src[e];
        }
    }
}

// ---------------------------------------------------------------- weight convert+transpose
// wt[o][k] (bf16, [64][512]) = W[k][o]  where k = r*64+i  (W flat is [512][64])
__global__ __launch_bounds__(256) void convw_kernel(
    const float* __restrict__ W, unsigned short* __restrict__ wt)
{
    int idx = blockIdx.x * 256 + threadIdx.x;
    if (idx >= 64 * 512) return;
    int o = idx >> 9, k = idx & 511;
    wt[idx] = bf16_rne(W[(long)k * 64 + o]);
}

// ---------------------------------------------------------------- x -> bf16
__global__ __launch_bounds__(256) void convx_kernel(
    const float4* __restrict__ x, unsigned short* __restrict__ xb, int n8)
{
    int i = blockIdx.x * 256 + threadIdx.x;
    if (i >= n8) return;
    float4 v0 = x[i * 2], v1 = x[i * 2 + 1];
    us8 o;
    o[0] = bf16_rne(v0.x); o[1] = bf16_rne(v0.y);
    o[2] = bf16_rne(v0.z); o[3] = bf16_rne(v0.w);
    o[4] = bf16_rne(v1.x); o[5] = bf16_rne(v1.y);
    o[6] = bf16_rne(v1.z); o[7] = bf16_rne(v1.w);
    *(us8*)(xb + (long)i * 8) = o;
}

// ---------------------------------------------------------------- gather
// 16 lanes per segment; lane owns 4 features (ushort4 = 8 B/lane).
// 4 segments per wave, grid-stride persistent.
__global__ __launch_bounds__(256) void gather_kernel(
    const unsigned short* __restrict__ xb, const int* __restrict__ offsets,
    const int* __restrict__ perm, unsigned short* __restrict__ agbf,
    int S, int nNodes)
{
    int tid = threadIdx.x;
    int gidx = (blockIdx.x * 256 + tid) >> 4;
    int nGroups = (gridDim.x * 256) >> 4;
    int fl = tid & 15;

    for (int s = gidx; s < S; s += nGroups) {
        int beg = offsets[s], end = offsets[s + 1];
        float a0 = 0.f, a1 = 0.f, a2 = 0.f, a3 = 0.f;
        for (int p = beg; p < end; ++p) {
            int srcn = perm[p];
            ushort4 v = *(const ushort4*)(xb + (long)srcn * ND + fl * 4);
            a0 += bf16_to_f(v.x); a1 += bf16_to_f(v.y);
            a2 += bf16_to_f(v.z); a3 += bf16_to_f(v.w);
        }
        int r = s / nNodes;
        int node = s - r * nNodes;
        ushort4 o;
        o.x = bf16_rne(a0); o.y = bf16_rne(a1);
        o.z = bf16_rne(a2); o.w = bf16_rne(a3);
        *(ushort4*)(agbf + (long)node * 512 + r * ND + fl * 4) = o;
    }
}

// ---------------------------------------------------------------- MFMA einsum
// msgs[M=nodes, 64] = A[M, 512] @ Wt^T   (A = agbf, Wt = [64][512] bf16)
__global__ __launch_bounds__(256) void einsum_kernel(
    const unsigned short* __restrict__ agbf, const unsigned short* __restrict__ wt,
    float* __restrict__ msgs, int nNodes)
{
    int wid = blockIdx.x * 4 + (threadIdx.x >> 6);
    int lane = threadIdx.x & 63;
    int nbase = wid * 32;
    if (nbase >= nNodes) return;
    int r16 = lane & 15;
    int kg  = lane >> 4;

    f32x4 acc[2][4];
#pragma unroll
    for (int m = 0; m < 2; ++m)
#pragma unroll
        for (int j = 0; j < 4; ++j) acc[m][j] = (f32x4){0.f, 0.f, 0.f, 0.f};

    int n0 = nbase + r16;      if (n0 >= nNodes) n0 = nNodes - 1;
    int n1 = nbase + 16 + r16; if (n1 >= nNodes) n1 = nNodes - 1;
    const unsigned short* a0p = agbf + (long)n0 * 512 + kg * 8;
    const unsigned short* a1p = agbf + (long)n1 * 512 + kg * 8;
    const unsigned short* bp  = wt + (long)r16 * 512 + kg * 8;

#pragma unroll 4
    for (int kk = 0; kk < 16; ++kk) {
        bf16x8 a0 = *(const bf16x8*)(a0p + kk * 32);
        bf16x8 a1 = *(const bf16x8*)(a1p + kk * 32);
#pragma unroll
        for (int j = 0; j < 4; ++j) {
            bf16x8 b = *(const bf16x8*)(bp + (long)j * 16 * 512 + kk * 32);
            acc[0][j] = __builtin_amdgcn_mfma_f32_16x16x32_bf16(a0, b, acc[0][j], 0, 0, 0);
            acc[1][j] = __builtin_amdgcn_mfma_f32_16x16x32_bf16(a1, b, acc[1][j], 0, 0, 0);
        }
    }

    // C layout (verified m89): col = lane&15, row = (lane>>4)*4 + reg
#pragma unroll
    for (int m = 0; m < 2; ++m) {
#pragma unroll
        for (int reg = 0; reg < 4; ++reg) {
            int row = nbase + m * 16 + kg * 4 + reg;
            if (row < nNodes) {
#pragma unroll
                for (int j = 0; j < 4; ++j)
                    msgs[(long)row * ND + j * 16 + r16] = acc[m][j][reg];
            }
        }
    }
}

// ---------------------------------------------------------------- MLP (quad structure)
__global__ __launch_bounds__(256, 2) void mlp_kernel(
    const float* __restrict__ xin, const float* __restrict__ msgs,
    const float* __restrict__ bias, const float* __restrict__ eps,
    const float* __restrict__ mw1, const float* __restrict__ mb1,
    const float* __restrict__ mw2, const float* __restrict__ mb2,
    float* __restrict__ out, unsigned short* __restrict__ out_bf, int nNodes)
{
    __shared__ float w_lds[ND * ND];

    int tid  = threadIdx.x;
    int lane = tid & 63;
    int quad = tid & 3;
    int nl   = tid >> 2;
    int node = blockIdx.x * 64 + nl;
    bool active = node < nNodes;
    int nc = active ? node : (nNodes - 1);

    float epsv = 1.0f + eps[0];
    int obase = quad * 16;

    float h[16];
    {
        const float4* xr = (const float4*)(xin + (long)nc * ND + obase);
        const float4* mr = (const float4*)(msgs + (long)nc * ND + obase);
#pragma unroll
        for (int k = 0; k < 4; ++k) {
            float4 v = xr[k], m = mr[k];
            h[4 * k + 0] = fmaf(epsv, v.x, m.x); h[4 * k + 1] = fmaf(epsv, v.y, m.y);
            h[4 * k + 2] = fmaf(epsv, v.z, m.z); h[4 * k + 3] = fmaf(epsv, v.w, m.w);
        }
    }

    {
        const float4* wg = (const float4*)mw1 + tid * 4;
        float4* wl = (float4*)w_lds + tid * 4;
#pragma unroll
        for (int k = 0; k < 4; ++k) wl[k] = wg[k];
    }
    float t[16];
    {
        const float4* br = (const float4*)(mb1 + obase);
#pragma unroll
        for (int k = 0; k < 4; ++k) {
            float4 v = br[k];
            t[4 * k + 0] = v.x; t[4 * k + 1] = v.y;
            t[4 * k + 2] = v.z; t[4 * k + 3] = v.w;
        }
    }
    __syncthreads();
#pragma unroll
    for (int i = 0; i < ND; ++i) {
        float hi = __shfl(h[i & 15], (lane & 60) | (i >> 4));
        const float4* wr4 = (const float4*)(w_lds + i * ND + obase);
        float4 w0 = wr4[0], w1 = wr4[1], w2 = wr4[2], w3 = wr4[3];
        t[0]  = fmaf(hi, w0.x, t[0]);  t[1]  = fmaf(hi, w0.y, t[1]);
        t[2]  = fmaf(hi, w0.z, t[2]);  t[3]  = fmaf(hi, w0.w, t[3]);
        t[4]  = fmaf(hi, w1.x, t[4]);  t[5]  = fmaf(hi, w1.y, t[5]);
        t[6]  = fmaf(hi, w1.z, t[6]);  t[7]  = fmaf(hi, w1.w, t[7]);
        t[8]  = fmaf(hi, w2.x, t[8]);  t[9]  = fmaf(hi, w2.y, t[9]);
        t[10] = fmaf(hi, w2.z, t[10]); t[11] = fmaf(hi, w2.w, t[11]);
        t[12] = fmaf(hi, w3.x, t[12]); t[13] = fmaf(hi, w3.y, t[13]);
        t[14] = fmaf(hi, w3.z, t[14]); t[15] = fmaf(hi, w3.w, t[15]);
    }
#pragma unroll
    for (int j = 0; j < 16; ++j) t[j] = fmaxf(t[j], 0.f);

    __syncthreads();
    {
        const float4* wg = (const float4*)mw2 + tid * 4;
        float4* wl = (float4*)w_lds + tid * 4;
#pragma unroll
        for (int k = 0; k < 4; ++k) wl[k] = wg[k];
    }
    float o[16];
    {
        const float4* b2r = (const float4*)(mb2 + obase);
        const float4* bbr = (const float4*)(bias + obase);
#pragma unroll
        for (int k = 0; k < 4; ++k) {
            float4 v = b2r[k], u = bbr[k];
            o[4 * k + 0] = v.x + u.x; o[4 * k + 1] = v.y + u.y;
            o[4 * k + 2] = v.z + u.z; o[4 * k + 3] = v.w + u.w;
        }
    }
    __syncthreads();
#pragma unroll
    for (int i = 0; i < ND; ++i) {
        float ti = __shfl(t[i & 15], (lane & 60) | (i >> 4));
        const float4* wr4 = (const float4*)(w_lds + i * ND + obase);
        float4 w0 = wr4[0], w1 = wr4[1], w2 = wr4[2], w3 = wr4[3];
        o[0]  = fmaf(ti, w0.x, o[0]);  o[1]  = fmaf(ti, w0.y, o[1]);
        o[2]  = fmaf(ti, w0.z, o[2]);  o[3]  = fmaf(ti, w0.w, o[3]);
        o[4]  = fmaf(ti, w1.x, o[4]);  o[5]  = fmaf(ti, w1.y, o[5]);
        o[6]  = fmaf(ti, w1.z, o[6]);  o[7]  = fmaf(ti, w1.w, o[7]);
        o[8]  = fmaf(ti, w2.x, o[8]);  o[9]  = fmaf(ti, w2.y, o[9]);
        o[10] = fmaf(ti, w2.z, o[10]); o[11] = fmaf(ti, w2.w, o[11]);
        o[12] = fmaf(ti, w3.x, o[12]); o[13] = fmaf(ti, w3.y, o[13]);
        o[14] = fmaf(ti, w3.z, o[14]); o[15] = fmaf(ti, w3.w, o[15]);
    }

    if (!active) return;
    float4* outr = (float4*)(out + (long)node * ND + obase);
#pragma unroll
    for (int k = 0; k < 4; ++k)
        outr[k] = make_float4(o[4 * k + 0], o[4 * k + 1], o[4 * k + 2], o[4 * k + 3]);
    if (out_bf != nullptr) {
        us8 b0, b1;
#pragma unroll
        for (int k = 0; k < 8; ++k) { b0[k] = bf16_rne(o[k]); b1[k] = bf16_rne(o[8 + k]); }
        us8* obr = (us8*)(out_bf + (long)node * ND + obase);
        obr[0] = b0; obr[1] = b1;
    }
}

// ---------------------------------------------------------------- launch
extern "C" void kernel_launch(void* const* d_in, const int* in_sizes, int n_in,
                              void* d_out, int out_size, void* d_ws, size_t ws_size,
                              hipStream_t stream) {
    const float* x    = (const float*)d_in[0];
    const int* esrc   = (const int*)d_in[1];
    const int* edst   = (const int*)d_in[2];
    const int* etyp   = (const int*)d_in[3];

    const float* W1   = (const float*)d_in[4];
    const float* b1   = (const float*)d_in[5];
    const float* e1   = (const float*)d_in[6];
    const float* m1w1 = (const float*)d_in[7];
    const float* m1b1 = (const float*)d_in[8];
    const float* m1w2 = (const float*)d_in[9];
    const float* m1b2 = (const float*)d_in[10];

    const float* W2   = (const float*)d_in[11];
    const float* b2   = (const float*)d_in[12];
    const float* e2   = (const float*)d_in[13];
    const float* m2w1 = (const float*)d_in[14];
    const float* m2b1 = (const float*)d_in[15];
    const float* m2w2 = (const float*)d_in[16];
    const float* m2b2 = (const float*)d_in[17];

    int nNodes = in_sizes[0] / ND;   // 50000
    int nEdges = in_sizes[1];        // 1600000
    int S = NR * nNodes;             // 400000
    int nb = (S + SCAN_ELEMS - 1) / SCAN_ELEMS;

    // ---- workspace layout
    unsigned short* agbf = (unsigned short*)d_ws;                 // N*512 bf16
    float* msgs   = (float*)(agbf + (long)nNodes * 512);          // N*64 f32
    unsigned short* xhbf = (unsigned short*)(msgs + (long)nNodes * ND); // N*64 bf16
    unsigned short* wt1 = xhbf + (long)nNodes * ND;               // 64*512 bf16
    unsigned short* wt2 = wt1 + 64 * 512;
    int* offsets = (int*)(wt2 + 64 * 512);                        // S+1
    int* cnt_cur = offsets + (S + 1);                             // S
    int* blockSums = cnt_cur + S;
    int* blockOffs = blockSums + 512;
    int* perm = blockOffs + 512;                                  // E
    float* h    = (float*)d_out;
    float* outp = (float*)d_out;

    int egrid = (nEdges + 255) / 256;
    int ggrid = 2048;
    int mgrid = (nNodes + 63) / 64;
    int esgrid = ((nNodes + 31) / 32 + 3) / 4;
    int n8 = nNodes * ND / 8;
    int chunkSize = (nEdges + 255) / 256;    // 256 chunks
    int sliceSize = (nNodes + 7) / 8;        // 8 dst-slices

    // ---- build CSR once
    zeroi_kernel<<<512, 256, 0, stream>>>(cnt_cur, S);
    hist_kernel<<<egrid, 256, 0, stream>>>(edst, etyp, cnt_cur, nEdges, nNodes);
    scan1_kernel<<<nb, SCAN_BLOCK, 0, stream>>>(cnt_cur, offsets, blockSums, S);
    scan2_kernel<<<1, 512, 0, stream>>>(blockSums, blockOffs, nb);
    scan3_kernel<<<nb, SCAN_BLOCK, 0, stream>>>(offsets, cnt_cur, blockOffs, S, nEdges);
    permute_kernel<<<256 * 8, 256, 0, stream>>>(esrc, edst, etyp, cnt_cur, perm,
                                                nEdges, nNodes, chunkSize, sliceSize);

    // ---- weight + x converts
    convw_kernel<<<128, 256, 0, stream>>>(W1, wt1);
    convw_kernel<<<128, 256, 0, stream>>>(W2, wt2);
    convx_kernel<<<(n8 + 255) / 256, 256, 0, stream>>>((const float4*)x, xhbf, n8);

    // ---- layer 1
    gather_kernel<<<ggrid, 256, 0, stream>>>(xhbf, offsets, perm, agbf, S, nNodes);
    einsum_kernel<<<esgrid, 256, 0, stream>>>(agbf, wt1, msgs, nNodes);
    mlp_kernel<<<mgrid, 256, 0, stream>>>(x, msgs, b1, e1, m1w1, m1b1, m1w2, m1b2,
                                          h, xhbf, nNodes);

    // ---- layer 2
    gather_kernel<<<ggrid, 256, 0, stream>>>(xhbf, offsets, perm, agbf, S, nNodes);
    einsum_kernel<<<esgrid, 256, 0, stream>>>(agbf, wt2, msgs, nNodes);
    mlp_kernel<<<mgrid, 256, 0, stream>>>(h, msgs, b2, e2, m2w1, m2b1, m2w2, m2b2,
                                          outp, nullptr, nNodes);
}